// Round 5
// baseline (272.883 us; speedup 1.0000x reference)
//
#include <hip/hip_runtime.h>

#define Bn 32
#define Cc 128
#define Nn 307
#define Ll 12
#define LH 13
#define LAYERS 4
#define BN_EPS 1e-5f
#define SCW (Cc + 1)   // padded LDS stride
#define G1SZ ((size_t)2 * LAYERS * Bn * LH * Nn)

// ============================================================================
// G1[ch][l][b][t0][n] = sum_c X[b,c,n,t] * c1[l,c]
// grid (20 ntiles of 16, 32 b, 2 ch); block 256 = 16 n x 4 l x 4 c-splits.
// acc = 12 regs/thread (l is a LANE dim, not a register dim) -> 96 independent
// dwordx4 loads/thread stay in flight. 4 l-lanes read same addr (dedup'd).
// ============================================================================
#define NT1 16
__global__ __launch_bounds__(256, 4) void k_g1(const float* __restrict__ XL,
                                               const float* __restrict__ XH,
                                               const float* __restrict__ lc1,
                                               const float* __restrict__ hc1,
                                               float* __restrict__ G1) {
    __shared__ float s_c1[LAYERS * Cc];
    __shared__ float sred[12 * 260];  // [t][cs*64+g], stride 260
    int tile = blockIdx.x;  // 0..19
    int b = blockIdx.y;
    int ch = blockIdx.z;
    const float* X = ch ? XH : XL;
    const float* c1 = ch ? hc1 : lc1;
    int tid = threadIdx.x;
    for (int j = tid; j < LAYERS * Cc; j += 256) s_c1[j] = c1[j];
    __syncthreads();
    int nl = tid & 15;
    int l = (tid >> 4) & 3;
    int cs = tid >> 6;  // 0..3, 32 c each
    int n = tile * NT1 + nl;
    float4 a0 = {0.f, 0.f, 0.f, 0.f}, a1 = a0, a2 = a0;
    if (n < Nn) {
        const float* px = X + ((size_t)(b * Cc + cs * 32) * Nn + n) * Ll;
        const float* wp = s_c1 + l * Cc + cs * 32;
#pragma unroll 4
        for (int cc = 0; cc < 32; ++cc) {
            float4 v0 = *(const float4*)(px);
            float4 v1 = *(const float4*)(px + 4);
            float4 v2 = *(const float4*)(px + 8);
            float wv = wp[cc];
            a0.x += v0.x * wv; a0.y += v0.y * wv; a0.z += v0.z * wv; a0.w += v0.w * wv;
            a1.x += v1.x * wv; a1.y += v1.y * wv; a1.z += v1.z * wv; a1.w += v1.w * wv;
            a2.x += v2.x * wv; a2.y += v2.y * wv; a2.z += v2.z * wv; a2.w += v2.w * wv;
            px += (size_t)Nn * Ll;
        }
    }
    int g = tid & 63;  // nl + 16*l
    float av[12] = {a0.x, a0.y, a0.z, a0.w, a1.x, a1.y,
                    a1.z, a1.w, a2.x, a2.y, a2.z, a2.w};
#pragma unroll
    for (int t = 0; t < 12; ++t) sred[t * 260 + cs * 64 + g] = av[t];
    __syncthreads();
#pragma unroll
    for (int r = 0; r < 3; ++r) {  // 768 outputs = 3 * 256
        int o = r * 256 + tid;
        int og = o & 63, t = o >> 6;
        float v = sred[t * 260 + og] + sred[t * 260 + 64 + og] +
                  sred[t * 260 + 128 + og] + sred[t * 260 + 192 + og];
        int onl = og & 15, ol = og >> 4;
        int nn = tile * NT1 + onl;
        int t0 = ch ? (t + 1) : t;
        if (nn < Nn)
            G1[((size_t)(ch * LAYERS + ol) * Bn + b) * (LH * Nn) + (size_t)t0 * Nn + nn] = v;
    }
    if (tid < 64) {  // zero the unused t-plane (ch0: t0=12, ch1: t0=0)
        int onl = tid & 15, ol = tid >> 4;
        int nn = tile * NT1 + onl;
        int t0z = ch ? 0 : (LH - 1);
        if (nn < Nn)
            G1[((size_t)(ch * LAYERS + ol) * Bn + b) * (LH * Nn) + (size_t)t0z * Nn + nn] = 0.f;
    }
}

// ============================================================================
// G2[ch][l][b][t0][c] = sum_n X[b,c,n,t] * c2[l,n]
// grid (16 ctiles of 8, 32 b, 2 ch); block 256 = 8 c x 4 l x 8 n-stripes.
// Same register-wall fix: acc=12, ~115 independent loads/thread.
// ============================================================================
__global__ __launch_bounds__(256, 4) void k_g2(const float* __restrict__ XL,
                                               const float* __restrict__ XH,
                                               const float* __restrict__ lc2,
                                               const float* __restrict__ hc2,
                                               float* __restrict__ G2) {
    __shared__ float s_c2[LAYERS * Nn];
    __shared__ float sred[12 * 260];  // [t][ns*32+g]
    int ctile = blockIdx.x;  // 0..15 (8 c each)
    int b = blockIdx.y;
    int ch = blockIdx.z;
    const float* X = ch ? XH : XL;
    const float* c2 = ch ? hc2 : lc2;
    int tid = threadIdx.x;
    for (int j = tid; j < LAYERS * Nn; j += 256) s_c2[j] = c2[j];
    __syncthreads();
    int c8 = tid & 7;
    int l = (tid >> 3) & 3;
    int ns = tid >> 5;  // 0..7
    int c = ctile * 8 + c8;
    float4 a0 = {0.f, 0.f, 0.f, 0.f}, a1 = a0, a2 = a0;
    const float* pb = X + (size_t)(b * Cc + c) * Nn * Ll;
    const float* wp = s_c2 + l * Nn;
#pragma unroll 4
    for (int n = ns; n < Nn; n += 8) {
        const float* px = pb + (size_t)n * Ll;
        float4 v0 = *(const float4*)(px);
        float4 v1 = *(const float4*)(px + 4);
        float4 v2 = *(const float4*)(px + 8);
        float wv = wp[n];
        a0.x += v0.x * wv; a0.y += v0.y * wv; a0.z += v0.z * wv; a0.w += v0.w * wv;
        a1.x += v1.x * wv; a1.y += v1.y * wv; a1.z += v1.z * wv; a1.w += v1.w * wv;
        a2.x += v2.x * wv; a2.y += v2.y * wv; a2.z += v2.z * wv; a2.w += v2.w * wv;
    }
    float av[12] = {a0.x, a0.y, a0.z, a0.w, a1.x, a1.y,
                    a1.z, a1.w, a2.x, a2.y, a2.z, a2.w};
#pragma unroll
    for (int t = 0; t < 12; ++t) sred[t * 260 + tid] = av[t];  // tid = ns*32+g
    __syncthreads();
    size_t cb;
#pragma unroll
    for (int r = 0; r < 2; ++r) {  // 384 outputs = 256 + 128
        int o = r * 256 + tid;
        if (o < 384) {
            int og = o & 31, t = o >> 5;
            float v = 0.f;
#pragma unroll
            for (int s = 0; s < 8; ++s) v += sred[t * 260 + s * 32 + og];
            int oc8 = og & 7, ol = og >> 3;
            int t0 = ch ? (t + 1) : t;
            G2[((size_t)(ch * LAYERS + ol) * Bn + b) * (LH * Cc) + (size_t)t0 * Cc +
               ctile * 8 + oc8] = v;
        }
    }
    if (ch && tid < 32) {  // zero plane t0=0 for high channel
        int oc8 = tid & 7, ol = tid >> 3;
        G2[((size_t)(ch * LAYERS + ol) * Bn + b) * (LH * Cc) + ctile * 8 + oc8] = 0.f;
    }
}

// ============================================================================
// GW[ch][l][row=(b*LH+t0)][c] = sum_n G1[ch][l][row][n] * w[ch][l][n][c]
// grid (104 row-tiles of 4, 8 chl); block 256 = 32 c-quads x 8 n-stripes.
// ============================================================================
#define GWR 4
__global__ __launch_bounds__(256) void k_gw(const float* __restrict__ lw,
                                            const float* __restrict__ hw,
                                            const float* __restrict__ G1,
                                            float* __restrict__ GW) {
    __shared__ float sG1[GWR * Nn];
    __shared__ float sred[8][GWR][Cc];  // 16 KB
    int tile = blockIdx.x;  // 0..103
    int chl = blockIdx.y;   // ch*4 + l
    int ch = chl >> 2, l = chl & 3;
    const float* w = (ch ? hw : lw) + (size_t)l * Nn * Cc;
    const float* g1 = G1 + (size_t)chl * Bn * (LH * Nn) + (size_t)tile * GWR * Nn;
    int tid = threadIdx.x;
    for (int i = tid; i < GWR * Nn / 4; i += 256)
        ((float4*)sG1)[i] = ((const float4*)g1)[i];
    __syncthreads();
    int c4 = (tid & 31) * 4;  // c base
    int stripe = tid >> 5;    // 0..7
    float4 a0 = {0.f, 0.f, 0.f, 0.f}, a1 = a0, a2 = a0, a3 = a0;
#define GW_FMA(wv, nn)                                         \
    {                                                          \
        float g0 = sG1[0 * Nn + (nn)];                         \
        float g1v = sG1[1 * Nn + (nn)];                        \
        float g2v = sG1[2 * Nn + (nn)];                        \
        float g3v = sG1[3 * Nn + (nn)];                        \
        a0.x += wv.x * g0;  a0.y += wv.y * g0;                 \
        a0.z += wv.z * g0;  a0.w += wv.w * g0;                 \
        a1.x += wv.x * g1v; a1.y += wv.y * g1v;                \
        a1.z += wv.z * g1v; a1.w += wv.w * g1v;                \
        a2.x += wv.x * g2v; a2.y += wv.y * g2v;                \
        a2.z += wv.z * g2v; a2.w += wv.w * g2v;                \
        a3.x += wv.x * g3v; a3.y += wv.y * g3v;                \
        a3.z += wv.z * g3v; a3.w += wv.w * g3v;                \
    }
    int n = stripe;
    for (; n + 24 < Nn; n += 32) {  // 4 strided dwordx4 in flight
        float4 w0 = *(const float4*)(w + (size_t)n * Cc + c4);
        float4 w1 = *(const float4*)(w + (size_t)(n + 8) * Cc + c4);
        float4 w2 = *(const float4*)(w + (size_t)(n + 16) * Cc + c4);
        float4 w3 = *(const float4*)(w + (size_t)(n + 24) * Cc + c4);
        GW_FMA(w0, n);
        GW_FMA(w1, n + 8);
        GW_FMA(w2, n + 16);
        GW_FMA(w3, n + 24);
    }
    for (; n < Nn; n += 8) {
        float4 w0 = *(const float4*)(w + (size_t)n * Cc + c4);
        GW_FMA(w0, n);
    }
#undef GW_FMA
    *(float4*)&sred[stripe][0][c4] = a0;
    *(float4*)&sred[stripe][1][c4] = a1;
    *(float4*)&sred[stripe][2][c4] = a2;
    *(float4*)&sred[stripe][3][c4] = a3;
    __syncthreads();
    float* out = GW + (size_t)chl * Bn * (LH * Cc) + (size_t)tile * GWR * Cc;
    for (int o = tid; o < GWR * Cc; o += 256) {
        int r = o >> 7, cc = o & 127;
        float v = 0.f;
#pragma unroll
        for (int s = 0; s < 8; ++s) v += sred[s][r][cc];
        out[o] = v;
    }
}

// ============================================================================
// M[ch,l,b][t0][t1] = sum_c GW[ch,l,b,t0,c] * G2[ch,l,b,t1,c]
// ============================================================================
__global__ __launch_bounds__(256) void k_m(const float* __restrict__ GW,
                                           const float* __restrict__ G2,
                                           float* __restrict__ M) {
    __shared__ float sGW[LH][SCW];
    __shared__ float sG2[LH][SCW];
    int blk = blockIdx.x;  // (ch*LAYERS + l)*Bn + b
    int ch = blk >> 7;
    int T = ch ? LH : Ll;
    const float* gw = GW + (size_t)blk * (LH * Cc);
    const float* g2 = G2 + (size_t)blk * (LH * Cc);
    int tid = threadIdx.x;
    for (int i = tid; i < LH * Cc; i += 256) {
        int t = i >> 7, c = i & 127;
        sGW[t][c] = gw[i];
        sG2[t][c] = g2[i];
    }
    __syncthreads();
    float* Mo = M + (size_t)blk * (LH * LH);
    for (int i = tid; i < T * T; i += 256) {
        int t0 = i / T, t1 = i % T;
        float a = 0.f;
#pragma unroll 8
        for (int cc = 0; cc < Cc; ++cc) a += sGW[t0][cc] * sG2[t1][cc];
        Mo[t0 * LH + t1] = a;
    }
}

// ============================================================================
// Chain: 5 grid-wide launches (64 blocks = one per (ch,b)); kernel boundaries
// provide the cross-b sync BatchNorm needs. (unchanged, verified)
// ============================================================================
template <int T>
__device__ __forceinline__ void first_impl(int ch, int b,
                                           const float* __restrict__ M,
                                           const float* __restrict__ bb,
                                           const float* __restrict__ v,
                                           float* __restrict__ Lg,
                                           float* __restrict__ Stats) {
    const int TT = T * T;
    __shared__ float sS[LH * LH];
    __shared__ float sA[LH * LH];
    int tid = threadIdx.x;
    const float* Ml = M + ((size_t)(ch * LAYERS + 0) * Bn + b) * (LH * LH);
    if (tid < TT) {
        int t = tid / T, q = tid % T;
        float a = bb[tid] + Ml[t * LH + q];
        sS[tid] = 1.f / (1.f + expf(-a));
    }
    __syncthreads();
    if (tid < TT) {
        int t = tid / T, q = tid % T;
        float a = 0.f;
#pragma unroll
        for (int k = 0; k < T; ++k) a += v[t * T + k] * sS[k * T + q];
        sA[tid] = a;
        Lg[(size_t)(ch * Bn + b) * (LH * LH) + tid] = a;
    }
    __syncthreads();
    if (tid < T) {
        float s = 0.f, ss = 0.f;
#pragma unroll
        for (int t = 0; t < T; ++t) {
            float x = sA[t * T + tid];
            s += x;
            ss += x * x;
        }
        float* St = Stats + (size_t)(0 * 2 + ch) * 2 * (LH * Bn);
        St[tid * Bn + b] = s;
        St[LH * Bn + tid * Bn + b] = ss;
    }
}

__global__ __launch_bounds__(192) void k_first(const float* __restrict__ M,
                                               const float* __restrict__ lb,
                                               const float* __restrict__ lv,
                                               const float* __restrict__ hb,
                                               const float* __restrict__ hv,
                                               float* __restrict__ Lg,
                                               float* __restrict__ Stats) {
    int ch = blockIdx.x >> 5, b = blockIdx.x & 31;
    if (ch == 0)
        first_impl<Ll>(0, b, M, lb, lv, Lg, Stats);
    else
        first_impl<LH>(1, b, M, hb, hv, Lg, Stats);
}

template <int T>
__device__ __forceinline__ void mid_impl(int ch, int b, int l,
                                         const float* __restrict__ M,
                                         const float* __restrict__ bb_all,
                                         const float* __restrict__ v_all,
                                         const float* __restrict__ g_all,
                                         const float* __restrict__ be_all,
                                         float* __restrict__ Lg,
                                         float* __restrict__ Stats,
                                         float* __restrict__ Pws) {
    const int TT = T * T;
    __shared__ float sP[LH * LH], sC[LH * LH], sA[LH * LH], sB[LH * LH], sM[LH * LH];
    __shared__ float sMean[LH], sScale[LH], sShift[LH];
    int tid = threadIdx.x;
    bool first = (l == 0);
    float* Lgb = Lg + (size_t)(ch * Bn + b) * (LH * LH);
    float* Pb = Pws + (size_t)(ch * Bn + b) * (LH * LH);
    if (tid < T) {
        const float* St = Stats + (size_t)(l * 2 + ch) * 2 * (LH * Bn);
        float s = 0.f, ss = 0.f;
        for (int b2 = 0; b2 < Bn; ++b2) {
            s += St[tid * Bn + b2];
            ss += St[LH * Bn + tid * Bn + b2];
        }
        float inv = 1.f / (float)(Bn * T);
        float m = s * inv;
        float var = ss * inv - m * m;
        sMean[tid] = m;
        sScale[tid] = rsqrtf(var + BN_EPS) * g_all[l * T + tid];
        sShift[tid] = be_all[l * T + tid];
    }
    if (tid < TT) {
        sA[tid] = Lgb[tid];
        if (!first) sP[tid] = Pb[tid];
    }
    __syncthreads();
    if (tid < T) {
        float vals[T];
        float mx = -1e30f;
#pragma unroll
        for (int q = 0; q < T; ++q) {
            float x = (sA[tid * T + q] - sMean[q]) * sScale[q] + sShift[q];
            vals[q] = x;
            mx = fmaxf(mx, x);
        }
        float sm = 0.f;
#pragma unroll
        for (int q = 0; q < T; ++q) {
            vals[q] = expf(vals[q] - mx);
            sm += vals[q];
        }
        float inv = 1.f / sm;
#pragma unroll
        for (int q = 0; q < T; ++q) sC[tid * T + q] = vals[q] * inv;
    }
    __syncthreads();
    if (tid < TT) {
        int t0 = tid / T, q = tid % T;
        float a;
        if (first) {
            a = sC[q * T + t0];
        } else {
            a = 0.f;
#pragma unroll
            for (int t = 0; t < T; ++t) a += sP[t0 * T + t] * sC[q * T + t];
        }
        sB[tid] = a;
        Pb[tid] = a;
    }
    const float* Mn = M + ((size_t)(ch * LAYERS + l + 1) * Bn + b) * (LH * LH);
    for (int i = tid; i < T * LH; i += 192) sM[i] = Mn[i];
    __syncthreads();
    if (tid < TT) {
        int t = tid / T, t1 = tid % T;
        float a = 0.f;
#pragma unroll
        for (int t0 = 0; t0 < T; ++t0) a += sB[t0 * T + t] * sM[t0 * LH + t1];
        sA[tid] = a;
    }
    __syncthreads();
    const float* bbn = bb_all + (size_t)(l + 1) * TT;
    if (tid < TT) {
        int t = tid / T, q = tid % T;
        float a = bbn[tid];
#pragma unroll
        for (int t1 = 0; t1 < T; ++t1) a += sA[t * T + t1] * sB[t1 * T + q];
        sP[tid] = 1.f / (1.f + expf(-a));
    }
    __syncthreads();
    const float* vn = v_all + (size_t)(l + 1) * TT;
    if (tid < TT) {
        int t = tid / T, q = tid % T;
        float a = 0.f;
#pragma unroll
        for (int k = 0; k < T; ++k) a += vn[t * T + k] * sP[k * T + q];
        sA[tid] = a;
        Lgb[tid] = a;
    }
    __syncthreads();
    if (tid < T) {
        float s = 0.f, ss = 0.f;
#pragma unroll
        for (int t = 0; t < T; ++t) {
            float x = sA[t * T + tid];
            s += x;
            ss += x * x;
        }
        float* St = Stats + (size_t)((l + 1) * 2 + ch) * 2 * (LH * Bn);
        St[tid * Bn + b] = s;
        St[LH * Bn + tid * Bn + b] = ss;
    }
}

__global__ __launch_bounds__(192) void k_mid(const float* __restrict__ M,
                                             const float* __restrict__ lb,
                                             const float* __restrict__ lv,
                                             const float* __restrict__ lgam,
                                             const float* __restrict__ lbet,
                                             const float* __restrict__ hb,
                                             const float* __restrict__ hv,
                                             const float* __restrict__ hgam,
                                             const float* __restrict__ hbet,
                                             float* __restrict__ Lg,
                                             float* __restrict__ Stats,
                                             float* __restrict__ Pws, int l) {
    int ch = blockIdx.x >> 5, b = blockIdx.x & 31;
    if (ch == 0)
        mid_impl<Ll>(0, b, l, M, lb, lv, lgam, lbet, Lg, Stats, Pws);
    else
        mid_impl<LH>(1, b, l, M, hb, hv, hgam, hbet, Lg, Stats, Pws);
}

template <int T>
__device__ __forceinline__ void last_impl(int ch, int b,
                                          const float* __restrict__ g_all,
                                          const float* __restrict__ be_all,
                                          const float* __restrict__ Lg,
                                          const float* __restrict__ Stats,
                                          const float* __restrict__ Pws,
                                          float* __restrict__ Pcol) {
    const int TT = T * T;
    const int l = LAYERS - 1;
    __shared__ float sP[LH * LH], sC[LH * LH], sA[LH * LH], sB[LH * LH];
    __shared__ float sMean[LH], sScale[LH], sShift[LH];
    int tid = threadIdx.x;
    const float* Lgb = Lg + (size_t)(ch * Bn + b) * (LH * LH);
    const float* Pb = Pws + (size_t)(ch * Bn + b) * (LH * LH);
    if (tid < T) {
        const float* St = Stats + (size_t)(l * 2 + ch) * 2 * (LH * Bn);
        float s = 0.f, ss = 0.f;
        for (int b2 = 0; b2 < Bn; ++b2) {
            s += St[tid * Bn + b2];
            ss += St[LH * Bn + tid * Bn + b2];
        }
        float inv = 1.f / (float)(Bn * T);
        float m = s * inv;
        float var = ss * inv - m * m;
        sMean[tid] = m;
        sScale[tid] = rsqrtf(var + BN_EPS) * g_all[l * T + tid];
        sShift[tid] = be_all[l * T + tid];
    }
    if (tid < TT) {
        sA[tid] = Lgb[tid];
        sP[tid] = Pb[tid];
    }
    __syncthreads();
    if (tid < T) {
        float vals[T];
        float mx = -1e30f;
#pragma unroll
        for (int q = 0; q < T; ++q) {
            float x = (sA[tid * T + q] - sMean[q]) * sScale[q] + sShift[q];
            vals[q] = x;
            mx = fmaxf(mx, x);
        }
        float sm = 0.f;
#pragma unroll
        for (int q = 0; q < T; ++q) {
            vals[q] = expf(vals[q] - mx);
            sm += vals[q];
        }
        float inv = 1.f / sm;
#pragma unroll
        for (int q = 0; q < T; ++q) sC[tid * T + q] = vals[q] * inv;
    }
    __syncthreads();
    if (tid < TT) {
        int t0 = tid / T, q = tid % T;
        float a = 0.f;
#pragma unroll
        for (int t = 0; t < T; ++t) a += sP[t0 * T + t] * sC[q * T + t];
        sB[tid] = a;
    }
    __syncthreads();
    if (tid < T) Pcol[(size_t)ch * Bn * LH + b * LH + tid] = sB[tid * T + (T - 1)];
}

__global__ __launch_bounds__(192) void k_last(const float* __restrict__ lgam,
                                              const float* __restrict__ lbet,
                                              const float* __restrict__ hgam,
                                              const float* __restrict__ hbet,
                                              const float* __restrict__ Lg,
                                              const float* __restrict__ Stats,
                                              const float* __restrict__ Pws,
                                              float* __restrict__ Pcol) {
    int ch = blockIdx.x >> 5, b = blockIdx.x & 31;
    if (ch == 0)
        last_impl<Ll>(0, b, lgam, lbet, Lg, Stats, Pws, Pcol);
    else
        last_impl<LH>(1, b, hgam, hbet, Lg, Stats, Pws, Pcol);
}

// ---- final: residuals + alpha blend using last-column weights (unchanged) ----
__global__ __launch_bounds__(256) void k_final(const float* __restrict__ XL,
                                               const float* __restrict__ XH,
                                               const float* __restrict__ Pcol,
                                               const float* __restrict__ alpha,
                                               float* __restrict__ out) {
    __shared__ float s_pl[Ll];
    __shared__ float s_ph[LH];
    int b = blockIdx.y;
    int tid = threadIdx.x;
    if (tid < Ll) s_pl[tid] = Pcol[b * LH + tid];
    if (tid < LH) s_ph[tid] = Pcol[Bn * LH + b * LH + tid];
    __syncthreads();
    int cn = blockIdx.x * blockDim.x + tid;
    if (cn >= Cc * Nn) return;
    size_t idx = (size_t)b * Cc * Nn + cn;
    const float* pl = XL + idx * Ll;
    const float* ph = XH + idx * Ll;
    float accL = 0.f, accH = 0.f;
#pragma unroll
    for (int t = 0; t < Ll; ++t) {
        accL += pl[t] * s_pl[t];
        accH += ph[t] * s_ph[t + 1];  // high-channel t0=0 plane is the zero pad
    }
    float a = 1.f / (1.f + expf(-alpha[0]));
    float xl = pl[Ll - 1] + accL;
    float xh = ph[Ll - 1] + accH;
    out[idx] = a * xl + (1.f - a) * xh;
}

extern "C" void kernel_launch(void* const* d_in, const int* in_sizes, int n_in,
                              void* d_out, int out_size, void* d_ws, size_t ws_size,
                              hipStream_t stream) {
    const float* XL = (const float*)d_in[0];
    const float* XH = (const float*)d_in[1];
    const float* lc1 = (const float*)d_in[2];
    const float* lc2 = (const float*)d_in[3];
    const float* lw = (const float*)d_in[4];
    const float* lb = (const float*)d_in[5];
    const float* lv = (const float*)d_in[6];
    const float* lg = (const float*)d_in[7];
    const float* lbeta = (const float*)d_in[8];
    const float* hc1 = (const float*)d_in[9];
    const float* hc2 = (const float*)d_in[10];
    const float* hw = (const float*)d_in[11];
    const float* hb = (const float*)d_in[12];
    const float* hv = (const float*)d_in[13];
    const float* hg = (const float*)d_in[14];
    const float* hbeta = (const float*)d_in[15];
    const float* alpha = (const float*)d_in[16];
    float* out = (float*)d_out;

    float* ws = (float*)d_ws;
    float* G1 = ws;                                          // 2*4*32*13*307
    float* G2 = G1 + G1SZ;                                   // 2*4*32*13*128
    float* M = G2 + (size_t)2 * LAYERS * Bn * LH * Cc;       // 2*4*32*13*13
    float* Pcol = M + (size_t)2 * LAYERS * Bn * LH * LH;     // 2*32*13
    float* Stats = Pcol + (size_t)2 * Bn * LH;               // 16*13*32
    float* Lg = Stats + (size_t)4 * LAYERS * LH * Bn;        // 2*32*169
    float* Pws = Lg + (size_t)2 * Bn * LH * LH;              // 2*32*169
    float* GW = Pws + (size_t)2 * Bn * LH * LH;              // 2*4*32*13*128

    k_g1<<<dim3(20, 32, 2), 256, 0, stream>>>(XL, XH, lc1, hc1, G1);
    k_g2<<<dim3(16, 32, 2), 256, 0, stream>>>(XL, XH, lc2, hc2, G2);
    k_gw<<<dim3(104, 8), 256, 0, stream>>>(lw, hw, G1, GW);
    k_m<<<256, 256, 0, stream>>>(GW, G2, M);
    k_first<<<64, 192, 0, stream>>>(M, lb, lv, hb, hv, Lg, Stats);
    k_mid<<<64, 192, 0, stream>>>(M, lb, lv, lg, lbeta, hb, hv, hg, hbeta, Lg, Stats, Pws, 0);
    k_mid<<<64, 192, 0, stream>>>(M, lb, lv, lg, lbeta, hb, hv, hg, hbeta, Lg, Stats, Pws, 1);
    k_mid<<<64, 192, 0, stream>>>(M, lb, lv, lg, lbeta, hb, hv, hg, hbeta, Lg, Stats, Pws, 2);
    k_last<<<64, 192, 0, stream>>>(lg, lbeta, hg, hbeta, Lg, Stats, Pws, Pcol);
    k_final<<<dim3((Cc * Nn + 255) / 256, Bn), 256, 0, stream>>>(XL, XH, Pcol, alpha, out);
}

// Round 6
// 256.513 us; speedup vs baseline: 1.0638x; 1.0638x over previous
//
#include <hip/hip_runtime.h>

#define Bn 32
#define Cc 128
#define Nn 307
#define Ll 12
#define LH 13
#define LAYERS 4
#define BN_EPS 1e-5f
#define SCW (Cc + 1)   // padded LDS stride
#define G1SZ ((size_t)2 * LAYERS * Bn * LH * Nn)  // one G1 partial buffer
#define NF4 921        // float4s per (b,c) plane: 307*12/4

// ============================================================================
// G1p[cs][ch][l][b][t0][n] = sum_{c in half cs} X[b,c,n,t] * c1[l,c]
// Flat-streaming: thread owns f4 index f (n=f/3, tgroup=f%3); wave reads are
// 1KB CONTIGUOUS per instruction (fixes the 48B-stride line-throughput wall).
// grid (4 ftiles x 2 cs, 32 b, 2 ch) = 512 blocks; 4-deep rotating pipeline.
// ============================================================================
__global__ __launch_bounds__(256) void k_g1(const float* __restrict__ XL,
                                            const float* __restrict__ XH,
                                            const float* __restrict__ lc1,
                                            const float* __restrict__ hc1,
                                            float* __restrict__ G1) {
    __shared__ float s_c1t[Cc * 4];  // [c][l]
    int bx = blockIdx.x;
    int ft = bx & 3, cs = bx >> 2;
    int b = blockIdx.y, ch = blockIdx.z;
    const float* X = ch ? XH : XL;
    const float* c1 = ch ? hc1 : lc1;
    int tid = threadIdx.x;
    for (int j = tid; j < Cc * 4; j += 256) s_c1t[j] = c1[(j & 3) * Cc + (j >> 2)];
    __syncthreads();
    int f = ft * 256 + tid;
    bool act = f < NF4;
    int cbase = cs * 64;
    float4 a0 = {0.f, 0.f, 0.f, 0.f}, a1 = a0, a2 = a0, a3 = a0;
#define FMA16(xq, cidx)                                                        \
    {                                                                          \
        float4 wq = *(const float4*)&s_c1t[(cbase + (cidx)) * 4];              \
        a0.x += xq.x * wq.x; a0.y += xq.y * wq.x; a0.z += xq.z * wq.x; a0.w += xq.w * wq.x; \
        a1.x += xq.x * wq.y; a1.y += xq.y * wq.y; a1.z += xq.z * wq.y; a1.w += xq.w * wq.y; \
        a2.x += xq.x * wq.z; a2.y += xq.y * wq.z; a2.z += xq.z * wq.z; a2.w += xq.w * wq.z; \
        a3.x += xq.x * wq.w; a3.y += xq.y * wq.w; a3.z += xq.z * wq.w; a3.w += xq.w * wq.w; \
    }
    if (act) {
        const float4* px = (const float4*)X + (size_t)(b * Cc + cbase) * NF4 + f;
        float4 q0 = px[0], q1 = px[NF4], q2 = px[2 * NF4], q3 = px[3 * NF4];
        px += 4 * NF4;
        for (int c = 0; c < 56; c += 4) {  // body: use iter c..c+3, load c+4..c+7
            FMA16(q0, c);     q0 = px[0];
            FMA16(q1, c + 1); q1 = px[NF4];
            FMA16(q2, c + 2); q2 = px[2 * NF4];
            FMA16(q3, c + 3); q3 = px[3 * NF4];
            px += 4 * NF4;
        }
        FMA16(q0, 56); float4 r0 = px[0];
        FMA16(q1, 57); float4 r1 = px[NF4];
        FMA16(q2, 58); float4 r2 = px[2 * NF4];
        FMA16(q3, 59); float4 r3 = px[3 * NF4];
        FMA16(r0, 60); FMA16(r1, 61); FMA16(r2, 62); FMA16(r3, 63);
    }
#undef FMA16
    float* Gout = G1 + (size_t)cs * G1SZ;
    if (act) {
        int tg = f % 3, nn = f / 3;
        int t0b = 4 * tg + ch;  // t0 for j=0 (high channel shifted by left-pad)
        size_t base = ((size_t)(ch * LAYERS) * Bn + b) * (LH * Nn) + (size_t)t0b * Nn + nn;
        const size_t ls = (size_t)Bn * LH * Nn;
        Gout[base + 0 * ls + 0 * Nn] = a0.x; Gout[base + 0 * ls + 1 * Nn] = a0.y;
        Gout[base + 0 * ls + 2 * Nn] = a0.z; Gout[base + 0 * ls + 3 * Nn] = a0.w;
        Gout[base + 1 * ls + 0 * Nn] = a1.x; Gout[base + 1 * ls + 1 * Nn] = a1.y;
        Gout[base + 1 * ls + 2 * Nn] = a1.z; Gout[base + 1 * ls + 3 * Nn] = a1.w;
        Gout[base + 2 * ls + 0 * Nn] = a2.x; Gout[base + 2 * ls + 1 * Nn] = a2.y;
        Gout[base + 2 * ls + 2 * Nn] = a2.z; Gout[base + 2 * ls + 3 * Nn] = a2.w;
        Gout[base + 3 * ls + 0 * Nn] = a3.x; Gout[base + 3 * ls + 1 * Nn] = a3.y;
        Gout[base + 3 * ls + 2 * Nn] = a3.z; Gout[base + 3 * ls + 3 * Nn] = a3.w;
    }
    // zero the unused t-plane (ch0: t0=12, ch1: t0=0) for this tile's n-range
    int n0 = (ft * 256) / 3;
    int n1 = (ft * 256 + 255) / 3; if (n1 > 306) n1 = 306;
    int cnt = n1 - n0 + 1;
    int t0z = ch ? 0 : (LH - 1);
    for (int o = tid; o < 4 * cnt; o += 256) {
        int l = o / cnt, nn = n0 + o % cnt;
        Gout[((size_t)(ch * LAYERS + l) * Bn + b) * (LH * Nn) + (size_t)t0z * Nn + nn] = 0.f;
    }
}

// ============================================================================
// G2[ch][l][b][t0][c] = sum_n X[b,c,n,t] * c2[l,n]
// Block = one (c,b,ch) plane (8192 blocks, 192 thr; 192%3==0 -> fixed tgroup).
// 5 preloaded contiguous sweeps; LDS class-reduce over the 64 n-slots.
// ============================================================================
__global__ __launch_bounds__(192) void k_g2(const float* __restrict__ XL,
                                            const float* __restrict__ XH,
                                            const float* __restrict__ lc2,
                                            const float* __restrict__ hc2,
                                            float* __restrict__ G2) {
    __shared__ float s_c2t[Nn * 4];        // [n][l]
    __shared__ float sred2[4 * 12 * 64];   // [l][t][m]
    int c = blockIdx.x, b = blockIdx.y, ch = blockIdx.z;
    const float* X = ch ? XH : XL;
    const float* c2 = ch ? hc2 : lc2;
    int tid = threadIdx.x;
    for (int j = tid; j < Nn * 4; j += 192) s_c2t[j] = c2[(j & 3) * Nn + (j >> 2)];
    __syncthreads();
    const float4* pb = (const float4*)X + (size_t)(b * Cc + c) * NF4;
    float4 x0 = pb[tid];
    float4 x1 = pb[tid + 192];
    float4 x2 = pb[tid + 384];
    float4 x3 = pb[tid + 576];
    float4 x4 = {0.f, 0.f, 0.f, 0.f};
    if (tid + 768 < NF4) x4 = pb[tid + 768];
    float4 a0 = {0.f, 0.f, 0.f, 0.f}, a1 = a0, a2 = a0, a3 = a0;
#define PROC(xq, ff)                                                           \
    {                                                                          \
        int n = (ff) / 3; if (n > 306) n = 306;                                \
        float4 wq = *(const float4*)&s_c2t[n * 4];                             \
        a0.x += xq.x * wq.x; a0.y += xq.y * wq.x; a0.z += xq.z * wq.x; a0.w += xq.w * wq.x; \
        a1.x += xq.x * wq.y; a1.y += xq.y * wq.y; a1.z += xq.z * wq.y; a1.w += xq.w * wq.y; \
        a2.x += xq.x * wq.z; a2.y += xq.y * wq.z; a2.z += xq.z * wq.z; a2.w += xq.w * wq.z; \
        a3.x += xq.x * wq.w; a3.y += xq.y * wq.w; a3.z += xq.z * wq.w; a3.w += xq.w * wq.w; \
    }
    PROC(x0, tid);
    PROC(x1, tid + 192);
    PROC(x2, tid + 384);
    PROC(x3, tid + 576);
    PROC(x4, tid + 768);
#undef PROC
    int tg = tid % 3, m = tid / 3;  // class slot
    sred2[(0 * 12 + 4 * tg + 0) * 64 + m] = a0.x;
    sred2[(0 * 12 + 4 * tg + 1) * 64 + m] = a0.y;
    sred2[(0 * 12 + 4 * tg + 2) * 64 + m] = a0.z;
    sred2[(0 * 12 + 4 * tg + 3) * 64 + m] = a0.w;
    sred2[(1 * 12 + 4 * tg + 0) * 64 + m] = a1.x;
    sred2[(1 * 12 + 4 * tg + 1) * 64 + m] = a1.y;
    sred2[(1 * 12 + 4 * tg + 2) * 64 + m] = a1.z;
    sred2[(1 * 12 + 4 * tg + 3) * 64 + m] = a1.w;
    sred2[(2 * 12 + 4 * tg + 0) * 64 + m] = a2.x;
    sred2[(2 * 12 + 4 * tg + 1) * 64 + m] = a2.y;
    sred2[(2 * 12 + 4 * tg + 2) * 64 + m] = a2.z;
    sred2[(2 * 12 + 4 * tg + 3) * 64 + m] = a2.w;
    sred2[(3 * 12 + 4 * tg + 0) * 64 + m] = a3.x;
    sred2[(3 * 12 + 4 * tg + 1) * 64 + m] = a3.y;
    sred2[(3 * 12 + 4 * tg + 2) * 64 + m] = a3.z;
    sred2[(3 * 12 + 4 * tg + 3) * 64 + m] = a3.w;
    __syncthreads();
    if (tid < 48) {
        int l = tid / 12, t = tid % 12;
        const float* r = &sred2[(l * 12 + t) * 64];
        float v = 0.f;
#pragma unroll 16
        for (int k = 0; k < 64; ++k) v += r[k];
        int t0 = t + ch;
        G2[((size_t)(ch * LAYERS + l) * Bn + b) * (LH * Cc) + (size_t)t0 * Cc + c] = v;
    } else if (ch && tid < 52) {  // zero plane t0=0 for high channel
        int l = tid - 48;
        G2[((size_t)(ch * LAYERS + l) * Bn + b) * (LH * Cc) + c] = 0.f;
    }
}

// ============================================================================
// GW[ch][l][row=(b*LH+t0)][c] = sum_n (G1p0+G1p1)[ch][l][row][n] * w[ch][l][n][c]
// grid (104 row-tiles of 4, 8 chl); block 256 = 32 c-quads x 8 n-stripes.
// ============================================================================
#define GWR 4
__global__ __launch_bounds__(256) void k_gw(const float* __restrict__ lw,
                                            const float* __restrict__ hw,
                                            const float* __restrict__ G1,
                                            float* __restrict__ GW) {
    __shared__ float sG1[GWR * Nn];
    __shared__ float sred[8][GWR][Cc];  // 16 KB
    int tile = blockIdx.x;  // 0..103
    int chl = blockIdx.y;   // ch*4 + l
    int ch = chl >> 2, l = chl & 3;
    const float* w = (ch ? hw : lw) + (size_t)l * Nn * Cc;
    size_t g1off = (size_t)chl * Bn * (LH * Nn) + (size_t)tile * GWR * Nn;
    const float4* g1a = (const float4*)(G1 + g1off);
    const float4* g1b = (const float4*)(G1 + G1SZ + g1off);
    int tid = threadIdx.x;
    for (int i = tid; i < GWR * Nn / 4; i += 256) {
        float4 pa = g1a[i], pb = g1b[i];
        float4 s = {pa.x + pb.x, pa.y + pb.y, pa.z + pb.z, pa.w + pb.w};
        ((float4*)sG1)[i] = s;
    }
    __syncthreads();
    int c4 = (tid & 31) * 4;
    int stripe = tid >> 5;
    float4 a0 = {0.f, 0.f, 0.f, 0.f}, a1 = a0, a2 = a0, a3 = a0;
#define GW_FMA(wv, nn)                                         \
    {                                                          \
        float g0 = sG1[0 * Nn + (nn)];                         \
        float g1v = sG1[1 * Nn + (nn)];                        \
        float g2v = sG1[2 * Nn + (nn)];                        \
        float g3v = sG1[3 * Nn + (nn)];                        \
        a0.x += wv.x * g0;  a0.y += wv.y * g0;                 \
        a0.z += wv.z * g0;  a0.w += wv.w * g0;                 \
        a1.x += wv.x * g1v; a1.y += wv.y * g1v;                \
        a1.z += wv.z * g1v; a1.w += wv.w * g1v;                \
        a2.x += wv.x * g2v; a2.y += wv.y * g2v;                \
        a2.z += wv.z * g2v; a2.w += wv.w * g2v;                \
        a3.x += wv.x * g3v; a3.y += wv.y * g3v;                \
        a3.z += wv.z * g3v; a3.w += wv.w * g3v;                \
    }
    int n = stripe;
    for (; n + 24 < Nn; n += 32) {
        float4 w0 = *(const float4*)(w + (size_t)n * Cc + c4);
        float4 w1 = *(const float4*)(w + (size_t)(n + 8) * Cc + c4);
        float4 w2 = *(const float4*)(w + (size_t)(n + 16) * Cc + c4);
        float4 w3 = *(const float4*)(w + (size_t)(n + 24) * Cc + c4);
        GW_FMA(w0, n);
        GW_FMA(w1, n + 8);
        GW_FMA(w2, n + 16);
        GW_FMA(w3, n + 24);
    }
    for (; n < Nn; n += 8) {
        float4 w0 = *(const float4*)(w + (size_t)n * Cc + c4);
        GW_FMA(w0, n);
    }
#undef GW_FMA
    *(float4*)&sred[stripe][0][c4] = a0;
    *(float4*)&sred[stripe][1][c4] = a1;
    *(float4*)&sred[stripe][2][c4] = a2;
    *(float4*)&sred[stripe][3][c4] = a3;
    __syncthreads();
    float* out = GW + (size_t)chl * Bn * (LH * Cc) + (size_t)tile * GWR * Cc;
    for (int o = tid; o < GWR * Cc; o += 256) {
        int r = o >> 7, cc = o & 127;
        float v = 0.f;
#pragma unroll
        for (int s = 0; s < 8; ++s) v += sred[s][r][cc];
        out[o] = v;
    }
}

// ============================================================================
// M[ch,l,b][t0][t1] = sum_c GW[ch,l,b,t0,c] * G2[ch,l,b,t1,c]
// ============================================================================
__global__ __launch_bounds__(256) void k_m(const float* __restrict__ GW,
                                           const float* __restrict__ G2,
                                           float* __restrict__ M) {
    __shared__ float sGW[LH][SCW];
    __shared__ float sG2[LH][SCW];
    int blk = blockIdx.x;
    int ch = blk >> 7;
    int T = ch ? LH : Ll;
    const float* gw = GW + (size_t)blk * (LH * Cc);
    const float* g2 = G2 + (size_t)blk * (LH * Cc);
    int tid = threadIdx.x;
    for (int i = tid; i < LH * Cc; i += 256) {
        int t = i >> 7, c = i & 127;
        sGW[t][c] = gw[i];
        sG2[t][c] = g2[i];
    }
    __syncthreads();
    float* Mo = M + (size_t)blk * (LH * LH);
    for (int i = tid; i < T * T; i += 256) {
        int t0 = i / T, t1 = i % T;
        float a = 0.f;
#pragma unroll 8
        for (int cc = 0; cc < Cc; ++cc) a += sGW[t0][cc] * sG2[t1][cc];
        Mo[t0 * LH + t1] = a;
    }
}

// ============================================================================
// Chain: 5 grid-wide launches (64 blocks = one per (ch,b)). (unchanged)
// ============================================================================
template <int T>
__device__ __forceinline__ void first_impl(int ch, int b,
                                           const float* __restrict__ M,
                                           const float* __restrict__ bb,
                                           const float* __restrict__ v,
                                           float* __restrict__ Lg,
                                           float* __restrict__ Stats) {
    const int TT = T * T;
    __shared__ float sS[LH * LH];
    __shared__ float sA[LH * LH];
    int tid = threadIdx.x;
    const float* Ml = M + ((size_t)(ch * LAYERS + 0) * Bn + b) * (LH * LH);
    if (tid < TT) {
        int t = tid / T, q = tid % T;
        float a = bb[tid] + Ml[t * LH + q];
        sS[tid] = 1.f / (1.f + expf(-a));
    }
    __syncthreads();
    if (tid < TT) {
        int t = tid / T, q = tid % T;
        float a = 0.f;
#pragma unroll
        for (int k = 0; k < T; ++k) a += v[t * T + k] * sS[k * T + q];
        sA[tid] = a;
        Lg[(size_t)(ch * Bn + b) * (LH * LH) + tid] = a;
    }
    __syncthreads();
    if (tid < T) {
        float s = 0.f, ss = 0.f;
#pragma unroll
        for (int t = 0; t < T; ++t) {
            float x = sA[t * T + tid];
            s += x;
            ss += x * x;
        }
        float* St = Stats + (size_t)(0 * 2 + ch) * 2 * (LH * Bn);
        St[tid * Bn + b] = s;
        St[LH * Bn + tid * Bn + b] = ss;
    }
}

__global__ __launch_bounds__(192) void k_first(const float* __restrict__ M,
                                               const float* __restrict__ lb,
                                               const float* __restrict__ lv,
                                               const float* __restrict__ hb,
                                               const float* __restrict__ hv,
                                               float* __restrict__ Lg,
                                               float* __restrict__ Stats) {
    int ch = blockIdx.x >> 5, b = blockIdx.x & 31;
    if (ch == 0)
        first_impl<Ll>(0, b, M, lb, lv, Lg, Stats);
    else
        first_impl<LH>(1, b, M, hb, hv, Lg, Stats);
}

template <int T>
__device__ __forceinline__ void mid_impl(int ch, int b, int l,
                                         const float* __restrict__ M,
                                         const float* __restrict__ bb_all,
                                         const float* __restrict__ v_all,
                                         const float* __restrict__ g_all,
                                         const float* __restrict__ be_all,
                                         float* __restrict__ Lg,
                                         float* __restrict__ Stats,
                                         float* __restrict__ Pws) {
    const int TT = T * T;
    __shared__ float sP[LH * LH], sC[LH * LH], sA[LH * LH], sB[LH * LH], sM[LH * LH];
    __shared__ float sMean[LH], sScale[LH], sShift[LH];
    int tid = threadIdx.x;
    bool first = (l == 0);
    float* Lgb = Lg + (size_t)(ch * Bn + b) * (LH * LH);
    float* Pb = Pws + (size_t)(ch * Bn + b) * (LH * LH);
    if (tid < T) {
        const float* St = Stats + (size_t)(l * 2 + ch) * 2 * (LH * Bn);
        float s = 0.f, ss = 0.f;
        for (int b2 = 0; b2 < Bn; ++b2) {
            s += St[tid * Bn + b2];
            ss += St[LH * Bn + tid * Bn + b2];
        }
        float inv = 1.f / (float)(Bn * T);
        float m = s * inv;
        float var = ss * inv - m * m;
        sMean[tid] = m;
        sScale[tid] = rsqrtf(var + BN_EPS) * g_all[l * T + tid];
        sShift[tid] = be_all[l * T + tid];
    }
    if (tid < TT) {
        sA[tid] = Lgb[tid];
        if (!first) sP[tid] = Pb[tid];
    }
    __syncthreads();
    if (tid < T) {
        float vals[T];
        float mx = -1e30f;
#pragma unroll
        for (int q = 0; q < T; ++q) {
            float x = (sA[tid * T + q] - sMean[q]) * sScale[q] + sShift[q];
            vals[q] = x;
            mx = fmaxf(mx, x);
        }
        float sm = 0.f;
#pragma unroll
        for (int q = 0; q < T; ++q) {
            vals[q] = expf(vals[q] - mx);
            sm += vals[q];
        }
        float inv = 1.f / sm;
#pragma unroll
        for (int q = 0; q < T; ++q) sC[tid * T + q] = vals[q] * inv;
    }
    __syncthreads();
    if (tid < TT) {
        int t0 = tid / T, q = tid % T;
        float a;
        if (first) {
            a = sC[q * T + t0];
        } else {
            a = 0.f;
#pragma unroll
            for (int t = 0; t < T; ++t) a += sP[t0 * T + t] * sC[q * T + t];
        }
        sB[tid] = a;
        Pb[tid] = a;
    }
    const float* Mn = M + ((size_t)(ch * LAYERS + l + 1) * Bn + b) * (LH * LH);
    for (int i = tid; i < T * LH; i += 192) sM[i] = Mn[i];
    __syncthreads();
    if (tid < TT) {
        int t = tid / T, t1 = tid % T;
        float a = 0.f;
#pragma unroll
        for (int t0 = 0; t0 < T; ++t0) a += sB[t0 * T + t] * sM[t0 * LH + t1];
        sA[tid] = a;
    }
    __syncthreads();
    const float* bbn = bb_all + (size_t)(l + 1) * TT;
    if (tid < TT) {
        int t = tid / T, q = tid % T;
        float a = bbn[tid];
#pragma unroll
        for (int t1 = 0; t1 < T; ++t1) a += sA[t * T + t1] * sB[t1 * T + q];
        sP[tid] = 1.f / (1.f + expf(-a));
    }
    __syncthreads();
    const float* vn = v_all + (size_t)(l + 1) * TT;
    if (tid < TT) {
        int t = tid / T, q = tid % T;
        float a = 0.f;
#pragma unroll
        for (int k = 0; k < T; ++k) a += vn[t * T + k] * sP[k * T + q];
        sA[tid] = a;
        Lgb[tid] = a;
    }
    __syncthreads();
    if (tid < T) {
        float s = 0.f, ss = 0.f;
#pragma unroll
        for (int t = 0; t < T; ++t) {
            float x = sA[t * T + tid];
            s += x;
            ss += x * x;
        }
        float* St = Stats + (size_t)((l + 1) * 2 + ch) * 2 * (LH * Bn);
        St[tid * Bn + b] = s;
        St[LH * Bn + tid * Bn + b] = ss;
    }
}

__global__ __launch_bounds__(192) void k_mid(const float* __restrict__ M,
                                             const float* __restrict__ lb,
                                             const float* __restrict__ lv,
                                             const float* __restrict__ lgam,
                                             const float* __restrict__ lbet,
                                             const float* __restrict__ hb,
                                             const float* __restrict__ hv,
                                             const float* __restrict__ hgam,
                                             const float* __restrict__ hbet,
                                             float* __restrict__ Lg,
                                             float* __restrict__ Stats,
                                             float* __restrict__ Pws, int l) {
    int ch = blockIdx.x >> 5, b = blockIdx.x & 31;
    if (ch == 0)
        mid_impl<Ll>(0, b, l, M, lb, lv, lgam, lbet, Lg, Stats, Pws);
    else
        mid_impl<LH>(1, b, l, M, hb, hv, hgam, hbet, Lg, Stats, Pws);
}

template <int T>
__device__ __forceinline__ void last_impl(int ch, int b,
                                          const float* __restrict__ g_all,
                                          const float* __restrict__ be_all,
                                          const float* __restrict__ Lg,
                                          const float* __restrict__ Stats,
                                          const float* __restrict__ Pws,
                                          float* __restrict__ Pcol) {
    const int TT = T * T;
    const int l = LAYERS - 1;
    __shared__ float sP[LH * LH], sC[LH * LH], sA[LH * LH], sB[LH * LH];
    __shared__ float sMean[LH], sScale[LH], sShift[LH];
    int tid = threadIdx.x;
    const float* Lgb = Lg + (size_t)(ch * Bn + b) * (LH * LH);
    const float* Pb = Pws + (size_t)(ch * Bn + b) * (LH * LH);
    if (tid < T) {
        const float* St = Stats + (size_t)(l * 2 + ch) * 2 * (LH * Bn);
        float s = 0.f, ss = 0.f;
        for (int b2 = 0; b2 < Bn; ++b2) {
            s += St[tid * Bn + b2];
            ss += St[LH * Bn + tid * Bn + b2];
        }
        float inv = 1.f / (float)(Bn * T);
        float m = s * inv;
        float var = ss * inv - m * m;
        sMean[tid] = m;
        sScale[tid] = rsqrtf(var + BN_EPS) * g_all[l * T + tid];
        sShift[tid] = be_all[l * T + tid];
    }
    if (tid < TT) {
        sA[tid] = Lgb[tid];
        sP[tid] = Pb[tid];
    }
    __syncthreads();
    if (tid < T) {
        float vals[T];
        float mx = -1e30f;
#pragma unroll
        for (int q = 0; q < T; ++q) {
            float x = (sA[tid * T + q] - sMean[q]) * sScale[q] + sShift[q];
            vals[q] = x;
            mx = fmaxf(mx, x);
        }
        float sm = 0.f;
#pragma unroll
        for (int q = 0; q < T; ++q) {
            vals[q] = expf(vals[q] - mx);
            sm += vals[q];
        }
        float inv = 1.f / sm;
#pragma unroll
        for (int q = 0; q < T; ++q) sC[tid * T + q] = vals[q] * inv;
    }
    __syncthreads();
    if (tid < TT) {
        int t0 = tid / T, q = tid % T;
        float a = 0.f;
#pragma unroll
        for (int t = 0; t < T; ++t) a += sP[t0 * T + t] * sC[q * T + t];
        sB[tid] = a;
    }
    __syncthreads();
    if (tid < T) Pcol[(size_t)ch * Bn * LH + b * LH + tid] = sB[tid * T + (T - 1)];
}

__global__ __launch_bounds__(192) void k_last(const float* __restrict__ lgam,
                                              const float* __restrict__ lbet,
                                              const float* __restrict__ hgam,
                                              const float* __restrict__ hbet,
                                              const float* __restrict__ Lg,
                                              const float* __restrict__ Stats,
                                              const float* __restrict__ Pws,
                                              float* __restrict__ Pcol) {
    int ch = blockIdx.x >> 5, b = blockIdx.x & 31;
    if (ch == 0)
        last_impl<Ll>(0, b, lgam, lbet, Lg, Stats, Pws, Pcol);
    else
        last_impl<LH>(1, b, hgam, hbet, Lg, Stats, Pws, Pcol);
}

// ============================================================================
// final: residuals + alpha blend. Flat-streaming: 192 threads read 192
// contiguous f4 (covering 64 outputs); lane-triple LDS reduce; coalesced store.
// ============================================================================
__global__ __launch_bounds__(192) void k_final(const float* __restrict__ XL,
                                               const float* __restrict__ XH,
                                               const float* __restrict__ Pcol,
                                               const float* __restrict__ alpha,
                                               float* __restrict__ out) {
    __shared__ float s_pl[Ll];
    __shared__ float s_ph[LH];
    __shared__ float sfin[192];
    int b = blockIdx.y;
    int tid = threadIdx.x;
    if (tid < Ll) s_pl[tid] = Pcol[b * LH + tid];
    if (tid >= 64 && tid < 64 + LH) s_ph[tid - 64] = Pcol[Bn * LH + b * LH + (tid - 64)];
    __syncthreads();
    int F = blockIdx.x * 192 + tid;  // < 117888 (=614*192 exact)
    int tg = F % 3;
    const float4* pl4 = (const float4*)XL + (size_t)b * (Cc * Nn * 3) + F;
    const float4* ph4 = (const float4*)XH + (size_t)b * (Cc * Nn * 3) + F;
    float4 xl = *pl4;
    float4 xh = *ph4;
    float a = 1.f / (1.f + expf(-alpha[0]));
    const float* wl = &s_pl[4 * tg];
    const float* wh = &s_ph[4 * tg + 1];  // high-channel weights shifted (zero pad)
    float pL = xl.x * wl[0] + xl.y * wl[1] + xl.z * wl[2] + xl.w * wl[3];
    float pH = xh.x * wh[0] + xh.y * wh[1] + xh.z * wh[2] + xh.w * wh[3];
    float p = a * pL + (1.f - a) * pH;
    if (tg == 2) p += a * xl.w + (1.f - a) * xh.w;  // residual: t=11 element
    sfin[tid] = p;
    __syncthreads();
    if (tid < 64) {
        float v = sfin[3 * tid] + sfin[3 * tid + 1] + sfin[3 * tid + 2];
        out[(size_t)b * (Cc * Nn) + blockIdx.x * 64 + tid] = v;
    }
}

extern "C" void kernel_launch(void* const* d_in, const int* in_sizes, int n_in,
                              void* d_out, int out_size, void* d_ws, size_t ws_size,
                              hipStream_t stream) {
    const float* XL = (const float*)d_in[0];
    const float* XH = (const float*)d_in[1];
    const float* lc1 = (const float*)d_in[2];
    const float* lc2 = (const float*)d_in[3];
    const float* lw = (const float*)d_in[4];
    const float* lb = (const float*)d_in[5];
    const float* lv = (const float*)d_in[6];
    const float* lg = (const float*)d_in[7];
    const float* lbeta = (const float*)d_in[8];
    const float* hc1 = (const float*)d_in[9];
    const float* hc2 = (const float*)d_in[10];
    const float* hw = (const float*)d_in[11];
    const float* hb = (const float*)d_in[12];
    const float* hv = (const float*)d_in[13];
    const float* hg = (const float*)d_in[14];
    const float* hbeta = (const float*)d_in[15];
    const float* alpha = (const float*)d_in[16];
    float* out = (float*)d_out;

    float* ws = (float*)d_ws;
    float* G1 = ws;                                          // 2 partial buffers
    float* G2 = G1 + 2 * G1SZ;                               // 2*4*32*13*128
    float* M = G2 + (size_t)2 * LAYERS * Bn * LH * Cc;       // 2*4*32*13*13
    float* Pcol = M + (size_t)2 * LAYERS * Bn * LH * LH;     // 2*32*13
    float* Stats = Pcol + (size_t)2 * Bn * LH;               // 16*13*32
    float* Lg = Stats + (size_t)4 * LAYERS * LH * Bn;        // 2*32*169
    float* Pws = Lg + (size_t)2 * Bn * LH * LH;              // 2*32*169
    float* GW = Pws + (size_t)2 * Bn * LH * LH;              // 2*4*32*13*128

    k_g1<<<dim3(8, 32, 2), 256, 0, stream>>>(XL, XH, lc1, hc1, G1);
    k_g2<<<dim3(128, 32, 2), 192, 0, stream>>>(XL, XH, lc2, hc2, G2);
    k_gw<<<dim3(104, 8), 256, 0, stream>>>(lw, hw, G1, GW);
    k_m<<<256, 256, 0, stream>>>(GW, G2, M);
    k_first<<<64, 192, 0, stream>>>(M, lb, lv, hb, hv, Lg, Stats);
    k_mid<<<64, 192, 0, stream>>>(M, lb, lv, lg, lbeta, hb, hv, hg, hbeta, Lg, Stats, Pws, 0);
    k_mid<<<64, 192, 0, stream>>>(M, lb, lv, lg, lbeta, hb, hv, hg, hbeta, Lg, Stats, Pws, 1);
    k_mid<<<64, 192, 0, stream>>>(M, lb, lv, lg, lbeta, hb, hv, hg, hbeta, Lg, Stats, Pws, 2);
    k_last<<<64, 192, 0, stream>>>(lg, lbeta, hg, hbeta, Lg, Stats, Pws, Pcol);
    k_final<<<dim3(614, 32), 192, 0, stream>>>(XL, XH, Pcol, alpha, out);
}

// Round 7
// 233.322 us; speedup vs baseline: 1.1696x; 1.0994x over previous
//
#include <hip/hip_runtime.h>

#define Bn 32
#define Cc 128
#define Nn 307
#define Ll 12
#define LH 13
#define LAYERS 4
#define BN_EPS 1e-5f
#define SCW (Cc + 1)   // padded LDS stride
#define G1SZ ((size_t)2 * LAYERS * Bn * LH * Nn)  // one G1 partial buffer
#define NF4 921        // float4s per (b,c) plane: 307*12/4

// ============================================================================
// k_gx: fused G1 + G2 in ONE launch so both X read streams run CONCURRENTLY.
// blockIdx.x < 10  -> G1 part: (cs 2 x ft 5), 192 thr, 8-deep load pipeline
// blockIdx.x >= 10 -> G2 part: one (c,b,ch) plane per block (128 ctiles)
// ============================================================================
__global__ __launch_bounds__(192) void k_gx(const float* __restrict__ XL,
                                            const float* __restrict__ XH,
                                            const float* __restrict__ lc1,
                                            const float* __restrict__ hc1,
                                            const float* __restrict__ lc2,
                                            const float* __restrict__ hc2,
                                            float* __restrict__ G1,
                                            float* __restrict__ G2) {
    int bx = blockIdx.x;
    int b = blockIdx.y, ch = blockIdx.z;
    const float* X = ch ? XH : XL;
    int tid = threadIdx.x;
    if (bx < 10) {
        // ---------------- G1 partial: sum over 64 c's (cs half) --------------
        __shared__ float s_c1t[Cc * 4];  // [c][l]
        const float* c1 = ch ? hc1 : lc1;
        int ft = bx % 5, cs = bx / 5;
        for (int j = tid; j < Cc * 4; j += 192) s_c1t[j] = c1[(j & 3) * Cc + (j >> 2)];
        __syncthreads();
        int f = ft * 192 + tid;
        bool act = f < NF4;
        int cbase = cs * 64;
        float4 a0 = {0.f, 0.f, 0.f, 0.f}, a1 = a0, a2 = a0, a3 = a0;
#define FMA16(xq, cidx)                                                        \
    {                                                                          \
        float4 wq = *(const float4*)&s_c1t[(cbase + (cidx)) * 4];              \
        a0.x += xq.x * wq.x; a0.y += xq.y * wq.x; a0.z += xq.z * wq.x; a0.w += xq.w * wq.x; \
        a1.x += xq.x * wq.y; a1.y += xq.y * wq.y; a1.z += xq.z * wq.y; a1.w += xq.w * wq.y; \
        a2.x += xq.x * wq.z; a2.y += xq.y * wq.z; a2.z += xq.z * wq.z; a2.w += xq.w * wq.z; \
        a3.x += xq.x * wq.w; a3.y += xq.y * wq.w; a3.z += xq.z * wq.w; a3.w += xq.w * wq.w; \
    }
        if (act) {
            const float4* px = (const float4*)X + (size_t)(b * Cc + cbase) * NF4 + f;
            float4 q0 = px[0 * NF4], q1 = px[1 * NF4], q2 = px[2 * NF4], q3 = px[3 * NF4];
            float4 q4 = px[4 * NF4], q5 = px[5 * NF4], q6 = px[6 * NF4], q7 = px[7 * NF4];
            px += 8 * NF4;
            for (int c = 0; c < 48; c += 8) {  // use c..c+7, load c+8..c+15
                FMA16(q0, c + 0); q0 = px[0 * NF4];
                FMA16(q1, c + 1); q1 = px[1 * NF4];
                FMA16(q2, c + 2); q2 = px[2 * NF4];
                FMA16(q3, c + 3); q3 = px[3 * NF4];
                FMA16(q4, c + 4); q4 = px[4 * NF4];
                FMA16(q5, c + 5); q5 = px[5 * NF4];
                FMA16(q6, c + 6); q6 = px[6 * NF4];
                FMA16(q7, c + 7); q7 = px[7 * NF4];
                px += 8 * NF4;
            }
            FMA16(q0, 48); q0 = px[0 * NF4];
            FMA16(q1, 49); q1 = px[1 * NF4];
            FMA16(q2, 50); q2 = px[2 * NF4];
            FMA16(q3, 51); q3 = px[3 * NF4];
            FMA16(q4, 52); q4 = px[4 * NF4];
            FMA16(q5, 53); q5 = px[5 * NF4];
            FMA16(q6, 54); q6 = px[6 * NF4];
            FMA16(q7, 55); q7 = px[7 * NF4];
            FMA16(q0, 56); FMA16(q1, 57); FMA16(q2, 58); FMA16(q3, 59);
            FMA16(q4, 60); FMA16(q5, 61); FMA16(q6, 62); FMA16(q7, 63);
        }
#undef FMA16
        float* Gout = G1 + (size_t)cs * G1SZ;
        if (act) {
            int tg = f % 3, nn = f / 3;
            int t0b = 4 * tg + ch;  // high channel shifted by left-pad
            size_t base = ((size_t)(ch * LAYERS) * Bn + b) * (LH * Nn) + (size_t)t0b * Nn + nn;
            const size_t ls = (size_t)Bn * LH * Nn;
            Gout[base + 0 * ls + 0 * Nn] = a0.x; Gout[base + 0 * ls + 1 * Nn] = a0.y;
            Gout[base + 0 * ls + 2 * Nn] = a0.z; Gout[base + 0 * ls + 3 * Nn] = a0.w;
            Gout[base + 1 * ls + 0 * Nn] = a1.x; Gout[base + 1 * ls + 1 * Nn] = a1.y;
            Gout[base + 1 * ls + 2 * Nn] = a1.z; Gout[base + 1 * ls + 3 * Nn] = a1.w;
            Gout[base + 2 * ls + 0 * Nn] = a2.x; Gout[base + 2 * ls + 1 * Nn] = a2.y;
            Gout[base + 2 * ls + 2 * Nn] = a2.z; Gout[base + 2 * ls + 3 * Nn] = a2.w;
            Gout[base + 3 * ls + 0 * Nn] = a3.x; Gout[base + 3 * ls + 1 * Nn] = a3.y;
            Gout[base + 3 * ls + 2 * Nn] = a3.z; Gout[base + 3 * ls + 3 * Nn] = a3.w;
        }
        // zero the unused t-plane (ch0: t0=12, ch1: t0=0) for this tile's n-range
        int n0 = ft * 64;
        int n1 = ft * 64 + 63; if (n1 > 306) n1 = 306;
        int cnt = n1 - n0 + 1;
        int t0z = ch ? 0 : (LH - 1);
        for (int o = tid; o < 4 * cnt; o += 192) {
            int l = o / cnt, nn = n0 + o % cnt;
            Gout[((size_t)(ch * LAYERS + l) * Bn + b) * (LH * Nn) + (size_t)t0z * Nn + nn] = 0.f;
        }
    } else {
        // ---------------- G2: one (c,b,ch) plane, 5 preloaded sweeps ---------
        __shared__ float s_c2t[Nn * 4];        // [n][l]
        __shared__ float sred2[4 * 12 * 64];   // [l][t][m]
        int c = bx - 10;
        const float* c2 = ch ? hc2 : lc2;
        for (int j = tid; j < Nn * 4; j += 192) s_c2t[j] = c2[(j & 3) * Nn + (j >> 2)];
        __syncthreads();
        const float4* pb = (const float4*)X + (size_t)(b * Cc + c) * NF4;
        float4 x0 = pb[tid];
        float4 x1 = pb[tid + 192];
        float4 x2 = pb[tid + 384];
        float4 x3 = pb[tid + 576];
        float4 x4 = {0.f, 0.f, 0.f, 0.f};
        if (tid + 768 < NF4) x4 = pb[tid + 768];
        float4 a0 = {0.f, 0.f, 0.f, 0.f}, a1 = a0, a2 = a0, a3 = a0;
#define PROC(xq, ff)                                                           \
    {                                                                          \
        int n = (ff) / 3; if (n > 306) n = 306;                                \
        float4 wq = *(const float4*)&s_c2t[n * 4];                             \
        a0.x += xq.x * wq.x; a0.y += xq.y * wq.x; a0.z += xq.z * wq.x; a0.w += xq.w * wq.x; \
        a1.x += xq.x * wq.y; a1.y += xq.y * wq.y; a1.z += xq.z * wq.y; a1.w += xq.w * wq.y; \
        a2.x += xq.x * wq.z; a2.y += xq.y * wq.z; a2.z += xq.z * wq.z; a2.w += xq.w * wq.z; \
        a3.x += xq.x * wq.w; a3.y += xq.y * wq.w; a3.z += xq.z * wq.w; a3.w += xq.w * wq.w; \
    }
        PROC(x0, tid);
        PROC(x1, tid + 192);
        PROC(x2, tid + 384);
        PROC(x3, tid + 576);
        PROC(x4, tid + 768);
#undef PROC
        int tg = tid % 3, m = tid / 3;
        sred2[(0 * 12 + 4 * tg + 0) * 64 + m] = a0.x;
        sred2[(0 * 12 + 4 * tg + 1) * 64 + m] = a0.y;
        sred2[(0 * 12 + 4 * tg + 2) * 64 + m] = a0.z;
        sred2[(0 * 12 + 4 * tg + 3) * 64 + m] = a0.w;
        sred2[(1 * 12 + 4 * tg + 0) * 64 + m] = a1.x;
        sred2[(1 * 12 + 4 * tg + 1) * 64 + m] = a1.y;
        sred2[(1 * 12 + 4 * tg + 2) * 64 + m] = a1.z;
        sred2[(1 * 12 + 4 * tg + 3) * 64 + m] = a1.w;
        sred2[(2 * 12 + 4 * tg + 0) * 64 + m] = a2.x;
        sred2[(2 * 12 + 4 * tg + 1) * 64 + m] = a2.y;
        sred2[(2 * 12 + 4 * tg + 2) * 64 + m] = a2.z;
        sred2[(2 * 12 + 4 * tg + 3) * 64 + m] = a2.w;
        sred2[(3 * 12 + 4 * tg + 0) * 64 + m] = a3.x;
        sred2[(3 * 12 + 4 * tg + 1) * 64 + m] = a3.y;
        sred2[(3 * 12 + 4 * tg + 2) * 64 + m] = a3.z;
        sred2[(3 * 12 + 4 * tg + 3) * 64 + m] = a3.w;
        __syncthreads();
        if (tid < 48) {
            int l = tid / 12, t = tid % 12;
            const float* r = &sred2[(l * 12 + t) * 64];
            float v = 0.f;
#pragma unroll 16
            for (int k = 0; k < 64; ++k) v += r[k];
            int t0 = t + ch;
            G2[((size_t)(ch * LAYERS + l) * Bn + b) * (LH * Cc) + (size_t)t0 * Cc + c] = v;
        } else if (ch && tid < 52) {
            int l = tid - 48;
            G2[((size_t)(ch * LAYERS + l) * Bn + b) * (LH * Cc) + c] = 0.f;
        }
    }
}

// ============================================================================
// GW[ch][l][row=(b*LH+t0)][c] = sum_n (G1p0+G1p1)[ch][l][row][n] * w[ch][l][n][c]
// grid (104 row-tiles of 4, 8 chl); block 256 = 32 c-quads x 8 n-stripes.
// ============================================================================
#define GWR 4
__global__ __launch_bounds__(256) void k_gw(const float* __restrict__ lw,
                                            const float* __restrict__ hw,
                                            const float* __restrict__ G1,
                                            float* __restrict__ GW) {
    __shared__ float sG1[GWR * Nn];
    __shared__ float sred[8][GWR][Cc];  // 16 KB
    int tile = blockIdx.x;  // 0..103
    int chl = blockIdx.y;   // ch*4 + l
    int ch = chl >> 2, l = chl & 3;
    const float* w = (ch ? hw : lw) + (size_t)l * Nn * Cc;
    size_t g1off = (size_t)chl * Bn * (LH * Nn) + (size_t)tile * GWR * Nn;
    const float4* g1a = (const float4*)(G1 + g1off);
    const float4* g1b = (const float4*)(G1 + G1SZ + g1off);
    int tid = threadIdx.x;
    for (int i = tid; i < GWR * Nn / 4; i += 256) {
        float4 pa = g1a[i], pb = g1b[i];
        float4 s = {pa.x + pb.x, pa.y + pb.y, pa.z + pb.z, pa.w + pb.w};
        ((float4*)sG1)[i] = s;
    }
    __syncthreads();
    int c4 = (tid & 31) * 4;
    int stripe = tid >> 5;
    float4 a0 = {0.f, 0.f, 0.f, 0.f}, a1 = a0, a2 = a0, a3 = a0;
#define GW_FMA(wv, nn)                                         \
    {                                                          \
        float g0 = sG1[0 * Nn + (nn)];                         \
        float g1v = sG1[1 * Nn + (nn)];                        \
        float g2v = sG1[2 * Nn + (nn)];                        \
        float g3v = sG1[3 * Nn + (nn)];                        \
        a0.x += wv.x * g0;  a0.y += wv.y * g0;                 \
        a0.z += wv.z * g0;  a0.w += wv.w * g0;                 \
        a1.x += wv.x * g1v; a1.y += wv.y * g1v;                \
        a1.z += wv.z * g1v; a1.w += wv.w * g1v;                \
        a2.x += wv.x * g2v; a2.y += wv.y * g2v;                \
        a2.z += wv.z * g2v; a2.w += wv.w * g2v;                \
        a3.x += wv.x * g3v; a3.y += wv.y * g3v;                \
        a3.z += wv.z * g3v; a3.w += wv.w * g3v;                \
    }
    int n = stripe;
    for (; n + 24 < Nn; n += 32) {
        float4 w0 = *(const float4*)(w + (size_t)n * Cc + c4);
        float4 w1 = *(const float4*)(w + (size_t)(n + 8) * Cc + c4);
        float4 w2 = *(const float4*)(w + (size_t)(n + 16) * Cc + c4);
        float4 w3 = *(const float4*)(w + (size_t)(n + 24) * Cc + c4);
        GW_FMA(w0, n);
        GW_FMA(w1, n + 8);
        GW_FMA(w2, n + 16);
        GW_FMA(w3, n + 24);
    }
    for (; n < Nn; n += 8) {
        float4 w0 = *(const float4*)(w + (size_t)n * Cc + c4);
        GW_FMA(w0, n);
    }
#undef GW_FMA
    *(float4*)&sred[stripe][0][c4] = a0;
    *(float4*)&sred[stripe][1][c4] = a1;
    *(float4*)&sred[stripe][2][c4] = a2;
    *(float4*)&sred[stripe][3][c4] = a3;
    __syncthreads();
    float* out = GW + (size_t)chl * Bn * (LH * Cc) + (size_t)tile * GWR * Cc;
    for (int o = tid; o < GWR * Cc; o += 256) {
        int r = o >> 7, cc = o & 127;
        float v = 0.f;
#pragma unroll
        for (int s = 0; s < 8; ++s) v += sred[s][r][cc];
        out[o] = v;
    }
}

// ============================================================================
// k_m: M[ch,l,b] = GW . G2^T ; l==0 blocks additionally run the layer-0
// chain prologue (scores=sigmoid(bb+M), logits=v@scores, Stats partials)
// since M is block-local in LDS — saves the k_first launch.
// ============================================================================
__global__ __launch_bounds__(256) void k_m(const float* __restrict__ GW,
                                           const float* __restrict__ G2,
                                           const float* __restrict__ lb,
                                           const float* __restrict__ lv,
                                           const float* __restrict__ hb,
                                           const float* __restrict__ hv,
                                           float* __restrict__ M,
                                           float* __restrict__ Lg,
                                           float* __restrict__ Stats) {
    __shared__ float sGW[LH][SCW];
    __shared__ float sG2[LH][SCW];
    __shared__ float sMm[LH * LH];
    __shared__ float sS[LH * LH];
    __shared__ float sA[LH * LH];
    int blk = blockIdx.x;  // (ch*LAYERS + l)*Bn + b
    int ch = blk >> 7;
    int l = (blk >> 5) & 3;
    int b = blk & 31;
    int T = ch ? LH : Ll;
    const float* gw = GW + (size_t)blk * (LH * Cc);
    const float* g2 = G2 + (size_t)blk * (LH * Cc);
    int tid = threadIdx.x;
    for (int i = tid; i < LH * Cc; i += 256) {
        int t = i >> 7, c = i & 127;
        sGW[t][c] = gw[i];
        sG2[t][c] = g2[i];
    }
    __syncthreads();
    float* Mo = M + (size_t)blk * (LH * LH);
    if (tid < T * T) {
        int t0 = tid / T, t1 = tid % T;
        float a = 0.f;
#pragma unroll 8
        for (int cc = 0; cc < Cc; ++cc) a += sGW[t0][cc] * sG2[t1][cc];
        Mo[t0 * LH + t1] = a;
        sMm[t0 * LH + t1] = a;
    }
    if (l != 0) return;
    // ---- layer-0 prologue (first_impl) ----
    const float* bb = ch ? hb : lb;
    const float* v = ch ? hv : lv;
    __syncthreads();
    int TT = T * T;
    if (tid < TT) {
        int t = tid / T, q = tid % T;
        float a = bb[tid] + sMm[t * LH + q];
        sS[tid] = 1.f / (1.f + expf(-a));
    }
    __syncthreads();
    if (tid < TT) {
        int t = tid / T, q = tid % T;
        float a = 0.f;
        for (int k = 0; k < T; ++k) a += v[t * T + k] * sS[k * T + q];
        sA[tid] = a;
        Lg[(size_t)(ch * Bn + b) * (LH * LH) + tid] = a;
    }
    __syncthreads();
    if (tid < T) {
        float s = 0.f, ss = 0.f;
        for (int t = 0; t < T; ++t) {
            float x = sA[t * T + tid];
            s += x;
            ss += x * x;
        }
        float* St = Stats + (size_t)(0 * 2 + ch) * 2 * (LH * Bn);
        St[tid * Bn + b] = s;
        St[LH * Bn + tid * Bn + b] = ss;
    }
}

// ============================================================================
// Chain mids/last: grid-wide launches (64 blocks = one per (ch,b)).
// ============================================================================
template <int T>
__device__ __forceinline__ void mid_impl(int ch, int b, int l,
                                         const float* __restrict__ M,
                                         const float* __restrict__ bb_all,
                                         const float* __restrict__ v_all,
                                         const float* __restrict__ g_all,
                                         const float* __restrict__ be_all,
                                         float* __restrict__ Lg,
                                         float* __restrict__ Stats,
                                         float* __restrict__ Pws) {
    const int TT = T * T;
    __shared__ float sP[LH * LH], sC[LH * LH], sA[LH * LH], sB[LH * LH], sM[LH * LH];
    __shared__ float sMean[LH], sScale[LH], sShift[LH];
    int tid = threadIdx.x;
    bool first = (l == 0);
    float* Lgb = Lg + (size_t)(ch * Bn + b) * (LH * LH);
    float* Pb = Pws + (size_t)(ch * Bn + b) * (LH * LH);
    if (tid < T) {
        const float* St = Stats + (size_t)(l * 2 + ch) * 2 * (LH * Bn);
        float s = 0.f, ss = 0.f;
        for (int b2 = 0; b2 < Bn; ++b2) {
            s += St[tid * Bn + b2];
            ss += St[LH * Bn + tid * Bn + b2];
        }
        float inv = 1.f / (float)(Bn * T);
        float m = s * inv;
        float var = ss * inv - m * m;
        sMean[tid] = m;
        sScale[tid] = rsqrtf(var + BN_EPS) * g_all[l * T + tid];
        sShift[tid] = be_all[l * T + tid];
    }
    if (tid < TT) {
        sA[tid] = Lgb[tid];
        if (!first) sP[tid] = Pb[tid];
    }
    __syncthreads();
    if (tid < T) {
        float vals[T];
        float mx = -1e30f;
#pragma unroll
        for (int q = 0; q < T; ++q) {
            float x = (sA[tid * T + q] - sMean[q]) * sScale[q] + sShift[q];
            vals[q] = x;
            mx = fmaxf(mx, x);
        }
        float sm = 0.f;
#pragma unroll
        for (int q = 0; q < T; ++q) {
            vals[q] = expf(vals[q] - mx);
            sm += vals[q];
        }
        float inv = 1.f / sm;
#pragma unroll
        for (int q = 0; q < T; ++q) sC[tid * T + q] = vals[q] * inv;
    }
    __syncthreads();
    if (tid < TT) {
        int t0 = tid / T, q = tid % T;
        float a;
        if (first) {
            a = sC[q * T + t0];
        } else {
            a = 0.f;
#pragma unroll
            for (int t = 0; t < T; ++t) a += sP[t0 * T + t] * sC[q * T + t];
        }
        sB[tid] = a;
        Pb[tid] = a;
    }
    const float* Mn = M + ((size_t)(ch * LAYERS + l + 1) * Bn + b) * (LH * LH);
    for (int i = tid; i < T * LH; i += 192) sM[i] = Mn[i];
    __syncthreads();
    if (tid < TT) {
        int t = tid / T, t1 = tid % T;
        float a = 0.f;
#pragma unroll
        for (int t0 = 0; t0 < T; ++t0) a += sB[t0 * T + t] * sM[t0 * LH + t1];
        sA[tid] = a;
    }
    __syncthreads();
    const float* bbn = bb_all + (size_t)(l + 1) * TT;
    if (tid < TT) {
        int t = tid / T, q = tid % T;
        float a = bbn[tid];
#pragma unroll
        for (int t1 = 0; t1 < T; ++t1) a += sA[t * T + t1] * sB[t1 * T + q];
        sP[tid] = 1.f / (1.f + expf(-a));
    }
    __syncthreads();
    const float* vn = v_all + (size_t)(l + 1) * TT;
    if (tid < TT) {
        int t = tid / T, q = tid % T;
        float a = 0.f;
#pragma unroll
        for (int k = 0; k < T; ++k) a += vn[t * T + k] * sP[k * T + q];
        sA[tid] = a;
        Lgb[tid] = a;
    }
    __syncthreads();
    if (tid < T) {
        float s = 0.f, ss = 0.f;
#pragma unroll
        for (int t = 0; t < T; ++t) {
            float x = sA[t * T + tid];
            s += x;
            ss += x * x;
        }
        float* St = Stats + (size_t)((l + 1) * 2 + ch) * 2 * (LH * Bn);
        St[tid * Bn + b] = s;
        St[LH * Bn + tid * Bn + b] = ss;
    }
}

__global__ __launch_bounds__(192) void k_mid(const float* __restrict__ M,
                                             const float* __restrict__ lb,
                                             const float* __restrict__ lv,
                                             const float* __restrict__ lgam,
                                             const float* __restrict__ lbet,
                                             const float* __restrict__ hb,
                                             const float* __restrict__ hv,
                                             const float* __restrict__ hgam,
                                             const float* __restrict__ hbet,
                                             float* __restrict__ Lg,
                                             float* __restrict__ Stats,
                                             float* __restrict__ Pws, int l) {
    int ch = blockIdx.x >> 5, b = blockIdx.x & 31;
    if (ch == 0)
        mid_impl<Ll>(0, b, l, M, lb, lv, lgam, lbet, Lg, Stats, Pws);
    else
        mid_impl<LH>(1, b, l, M, hb, hv, hgam, hbet, Lg, Stats, Pws);
}

template <int T>
__device__ __forceinline__ void last_impl(int ch, int b,
                                          const float* __restrict__ g_all,
                                          const float* __restrict__ be_all,
                                          const float* __restrict__ Lg,
                                          const float* __restrict__ Stats,
                                          const float* __restrict__ Pws,
                                          float* __restrict__ Pcol) {
    const int TT = T * T;
    const int l = LAYERS - 1;
    __shared__ float sP[LH * LH], sC[LH * LH], sA[LH * LH], sB[LH * LH];
    __shared__ float sMean[LH], sScale[LH], sShift[LH];
    int tid = threadIdx.x;
    const float* Lgb = Lg + (size_t)(ch * Bn + b) * (LH * LH);
    const float* Pb = Pws + (size_t)(ch * Bn + b) * (LH * LH);
    if (tid < T) {
        const float* St = Stats + (size_t)(l * 2 + ch) * 2 * (LH * Bn);
        float s = 0.f, ss = 0.f;
        for (int b2 = 0; b2 < Bn; ++b2) {
            s += St[tid * Bn + b2];
            ss += St[LH * Bn + tid * Bn + b2];
        }
        float inv = 1.f / (float)(Bn * T);
        float m = s * inv;
        float var = ss * inv - m * m;
        sMean[tid] = m;
        sScale[tid] = rsqrtf(var + BN_EPS) * g_all[l * T + tid];
        sShift[tid] = be_all[l * T + tid];
    }
    if (tid < TT) {
        sA[tid] = Lgb[tid];
        sP[tid] = Pb[tid];
    }
    __syncthreads();
    if (tid < T) {
        float vals[T];
        float mx = -1e30f;
#pragma unroll
        for (int q = 0; q < T; ++q) {
            float x = (sA[tid * T + q] - sMean[q]) * sScale[q] + sShift[q];
            vals[q] = x;
            mx = fmaxf(mx, x);
        }
        float sm = 0.f;
#pragma unroll
        for (int q = 0; q < T; ++q) {
            vals[q] = expf(vals[q] - mx);
            sm += vals[q];
        }
        float inv = 1.f / sm;
#pragma unroll
        for (int q = 0; q < T; ++q) sC[tid * T + q] = vals[q] * inv;
    }
    __syncthreads();
    if (tid < TT) {
        int t0 = tid / T, q = tid % T;
        float a = 0.f;
#pragma unroll
        for (int t = 0; t < T; ++t) a += sP[t0 * T + t] * sC[q * T + t];
        sB[tid] = a;
    }
    __syncthreads();
    if (tid < T) Pcol[(size_t)ch * Bn * LH + b * LH + tid] = sB[tid * T + (T - 1)];
}

__global__ __launch_bounds__(192) void k_last(const float* __restrict__ lgam,
                                              const float* __restrict__ lbet,
                                              const float* __restrict__ hgam,
                                              const float* __restrict__ hbet,
                                              const float* __restrict__ Lg,
                                              const float* __restrict__ Stats,
                                              const float* __restrict__ Pws,
                                              float* __restrict__ Pcol) {
    int ch = blockIdx.x >> 5, b = blockIdx.x & 31;
    if (ch == 0)
        last_impl<Ll>(0, b, lgam, lbet, Lg, Stats, Pws, Pcol);
    else
        last_impl<LH>(1, b, hgam, hbet, Lg, Stats, Pws, Pcol);
}

// ============================================================================
// final: residuals + alpha blend; flat contiguous f4 streams + lane-triple
// LDS reduce; coalesced store. (unchanged, verified)
// ============================================================================
__global__ __launch_bounds__(192) void k_final(const float* __restrict__ XL,
                                               const float* __restrict__ XH,
                                               const float* __restrict__ Pcol,
                                               const float* __restrict__ alpha,
                                               float* __restrict__ out) {
    __shared__ float s_pl[Ll];
    __shared__ float s_ph[LH];
    __shared__ float sfin[192];
    int b = blockIdx.y;
    int tid = threadIdx.x;
    if (tid < Ll) s_pl[tid] = Pcol[b * LH + tid];
    if (tid >= 64 && tid < 64 + LH) s_ph[tid - 64] = Pcol[Bn * LH + b * LH + (tid - 64)];
    __syncthreads();
    int F = blockIdx.x * 192 + tid;
    int tg = F % 3;
    const float4* pl4 = (const float4*)XL + (size_t)b * (Cc * Nn * 3) + F;
    const float4* ph4 = (const float4*)XH + (size_t)b * (Cc * Nn * 3) + F;
    float4 xl = *pl4;
    float4 xh = *ph4;
    float a = 1.f / (1.f + expf(-alpha[0]));
    const float* wl = &s_pl[4 * tg];
    const float* wh = &s_ph[4 * tg + 1];
    float pL = xl.x * wl[0] + xl.y * wl[1] + xl.z * wl[2] + xl.w * wl[3];
    float pH = xh.x * wh[0] + xh.y * wh[1] + xh.z * wh[2] + xh.w * wh[3];
    float p = a * pL + (1.f - a) * pH;
    if (tg == 2) p += a * xl.w + (1.f - a) * xh.w;
    sfin[tid] = p;
    __syncthreads();
    if (tid < 64) {
        float v = sfin[3 * tid] + sfin[3 * tid + 1] + sfin[3 * tid + 2];
        out[(size_t)b * (Cc * Nn) + blockIdx.x * 64 + tid] = v;
    }
}

extern "C" void kernel_launch(void* const* d_in, const int* in_sizes, int n_in,
                              void* d_out, int out_size, void* d_ws, size_t ws_size,
                              hipStream_t stream) {
    const float* XL = (const float*)d_in[0];
    const float* XH = (const float*)d_in[1];
    const float* lc1 = (const float*)d_in[2];
    const float* lc2 = (const float*)d_in[3];
    const float* lw = (const float*)d_in[4];
    const float* lb = (const float*)d_in[5];
    const float* lv = (const float*)d_in[6];
    const float* lg = (const float*)d_in[7];
    const float* lbeta = (const float*)d_in[8];
    const float* hc1 = (const float*)d_in[9];
    const float* hc2 = (const float*)d_in[10];
    const float* hw = (const float*)d_in[11];
    const float* hb = (const float*)d_in[12];
    const float* hv = (const float*)d_in[13];
    const float* hg = (const float*)d_in[14];
    const float* hbeta = (const float*)d_in[15];
    const float* alpha = (const float*)d_in[16];
    float* out = (float*)d_out;

    float* ws = (float*)d_ws;
    float* G1 = ws;                                          // 2 partial buffers
    float* G2 = G1 + 2 * G1SZ;                               // 2*4*32*13*128
    float* M = G2 + (size_t)2 * LAYERS * Bn * LH * Cc;       // 2*4*32*13*13
    float* Pcol = M + (size_t)2 * LAYERS * Bn * LH * LH;     // 2*32*13
    float* Stats = Pcol + (size_t)2 * Bn * LH;               // 16*13*32
    float* Lg = Stats + (size_t)4 * LAYERS * LH * Bn;        // 2*32*169
    float* Pws = Lg + (size_t)2 * Bn * LH * LH;              // 2*32*169
    float* GW = Pws + (size_t)2 * Bn * LH * LH;              // 2*4*32*13*128

    k_gx<<<dim3(138, 32, 2), 192, 0, stream>>>(XL, XH, lc1, hc1, lc2, hc2, G1, G2);
    k_gw<<<dim3(104, 8), 256, 0, stream>>>(lw, hw, G1, GW);
    k_m<<<256, 256, 0, stream>>>(GW, G2, lb, lv, hb, hv, M, Lg, Stats);
    k_mid<<<64, 192, 0, stream>>>(M, lb, lv, lg, lbeta, hb, hv, hg, hbeta, Lg, Stats, Pws, 0);
    k_mid<<<64, 192, 0, stream>>>(M, lb, lv, lg, lbeta, hb, hv, hg, hbeta, Lg, Stats, Pws, 1);
    k_mid<<<64, 192, 0, stream>>>(M, lb, lv, lg, lbeta, hb, hv, hg, hbeta, Lg, Stats, Pws, 2);
    k_last<<<64, 192, 0, stream>>>(lg, lbeta, hg, hbeta, Lg, Stats, Pws, Pcol);
    k_final<<<dim3(614, 32), 192, 0, stream>>>(XL, XH, Pcol, alpha, out);
}

// Round 9
// 230.299 us; speedup vs baseline: 1.1849x; 1.0131x over previous
//
#include <hip/hip_runtime.h>

#define Bn 32
#define Cc 128
#define Nn 307
#define Ll 12
#define LH 13
#define LAYERS 4
#define BN_EPS 1e-5f
#define SCW (Cc + 1)   // padded LDS stride
#define G1SZ ((size_t)2 * LAYERS * Bn * LH * Nn)  // one G1 partial buffer
#define NF4 921        // float4s per (b,c) plane: 307*12/4

// ============================================================================
// k_gx: fused G1 + G2 in ONE launch (concurrent X read streams, verified r7).
// G2 epilogue: stride-65 sred2 (conflict-free) + 2-stage parallel reduce.
// ============================================================================
__global__ __launch_bounds__(192) void k_gx(const float* __restrict__ XL,
                                            const float* __restrict__ XH,
                                            const float* __restrict__ lc1,
                                            const float* __restrict__ hc1,
                                            const float* __restrict__ lc2,
                                            const float* __restrict__ hc2,
                                            float* __restrict__ G1,
                                            float* __restrict__ G2) {
    int bx = blockIdx.x;
    int b = blockIdx.y, ch = blockIdx.z;
    const float* X = ch ? XH : XL;
    int tid = threadIdx.x;
    if (bx < 10) {
        // ---------------- G1 partial: sum over 64 c's (cs half) --------------
        __shared__ float s_c1t[Cc * 4];  // [c][l]
        const float* c1 = ch ? hc1 : lc1;
        int ft = bx % 5, cs = bx / 5;
        for (int j = tid; j < Cc * 4; j += 192) s_c1t[j] = c1[(j & 3) * Cc + (j >> 2)];
        __syncthreads();
        int f = ft * 192 + tid;
        bool act = f < NF4;
        int cbase = cs * 64;
        float4 a0 = {0.f, 0.f, 0.f, 0.f}, a1 = a0, a2 = a0, a3 = a0;
#define FMA16(xq, cidx)                                                        \
    {                                                                          \
        float4 wq = *(const float4*)&s_c1t[(cbase + (cidx)) * 4];              \
        a0.x += xq.x * wq.x; a0.y += xq.y * wq.x; a0.z += xq.z * wq.x; a0.w += xq.w * wq.x; \
        a1.x += xq.x * wq.y; a1.y += xq.y * wq.y; a1.z += xq.z * wq.y; a1.w += xq.w * wq.y; \
        a2.x += xq.x * wq.z; a2.y += xq.y * wq.z; a2.z += xq.z * wq.z; a2.w += xq.w * wq.z; \
        a3.x += xq.x * wq.w; a3.y += xq.y * wq.w; a3.z += xq.z * wq.w; a3.w += xq.w * wq.w; \
    }
        if (act) {
            const float4* px = (const float4*)X + (size_t)(b * Cc + cbase) * NF4 + f;
            float4 q0 = px[0 * NF4], q1 = px[1 * NF4], q2 = px[2 * NF4], q3 = px[3 * NF4];
            float4 q4 = px[4 * NF4], q5 = px[5 * NF4], q6 = px[6 * NF4], q7 = px[7 * NF4];
            px += 8 * NF4;
            for (int c = 0; c < 48; c += 8) {  // use c..c+7, load c+8..c+15
                FMA16(q0, c + 0); q0 = px[0 * NF4];
                FMA16(q1, c + 1); q1 = px[1 * NF4];
                FMA16(q2, c + 2); q2 = px[2 * NF4];
                FMA16(q3, c + 3); q3 = px[3 * NF4];
                FMA16(q4, c + 4); q4 = px[4 * NF4];
                FMA16(q5, c + 5); q5 = px[5 * NF4];
                FMA16(q6, c + 6); q6 = px[6 * NF4];
                FMA16(q7, c + 7); q7 = px[7 * NF4];
                px += 8 * NF4;
            }
            FMA16(q0, 48); q0 = px[0 * NF4];
            FMA16(q1, 49); q1 = px[1 * NF4];
            FMA16(q2, 50); q2 = px[2 * NF4];
            FMA16(q3, 51); q3 = px[3 * NF4];
            FMA16(q4, 52); q4 = px[4 * NF4];
            FMA16(q5, 53); q5 = px[5 * NF4];
            FMA16(q6, 54); q6 = px[6 * NF4];
            FMA16(q7, 55); q7 = px[7 * NF4];
            FMA16(q0, 56); FMA16(q1, 57); FMA16(q2, 58); FMA16(q3, 59);
            FMA16(q4, 60); FMA16(q5, 61); FMA16(q6, 62); FMA16(q7, 63);
        }
#undef FMA16
        float* Gout = G1 + (size_t)cs * G1SZ;
        if (act) {
            int tg = f % 3, nn = f / 3;
            int t0b = 4 * tg + ch;  // high channel shifted by left-pad
            size_t base = ((size_t)(ch * LAYERS) * Bn + b) * (LH * Nn) + (size_t)t0b * Nn + nn;
            const size_t ls = (size_t)Bn * LH * Nn;
            Gout[base + 0 * ls + 0 * Nn] = a0.x; Gout[base + 0 * ls + 1 * Nn] = a0.y;
            Gout[base + 0 * ls + 2 * Nn] = a0.z; Gout[base + 0 * ls + 3 * Nn] = a0.w;
            Gout[base + 1 * ls + 0 * Nn] = a1.x; Gout[base + 1 * ls + 1 * Nn] = a1.y;
            Gout[base + 1 * ls + 2 * Nn] = a1.z; Gout[base + 1 * ls + 3 * Nn] = a1.w;
            Gout[base + 2 * ls + 0 * Nn] = a2.x; Gout[base + 2 * ls + 1 * Nn] = a2.y;
            Gout[base + 2 * ls + 2 * Nn] = a2.z; Gout[base + 2 * ls + 3 * Nn] = a2.w;
            Gout[base + 3 * ls + 0 * Nn] = a3.x; Gout[base + 3 * ls + 1 * Nn] = a3.y;
            Gout[base + 3 * ls + 2 * Nn] = a3.z; Gout[base + 3 * ls + 3 * Nn] = a3.w;
        }
        // zero the unused t-plane (ch0: t0=12, ch1: t0=0) for this tile's n-range
        int n0 = ft * 64;
        int n1 = ft * 64 + 63; if (n1 > 306) n1 = 306;
        int cnt = n1 - n0 + 1;
        int t0z = ch ? 0 : (LH - 1);
        for (int o = tid; o < 4 * cnt; o += 192) {
            int l = o / cnt, nn = n0 + o % cnt;
            Gout[((size_t)(ch * LAYERS + l) * Bn + b) * (LH * Nn) + (size_t)t0z * Nn + nn] = 0.f;
        }
    } else {
        // ---------------- G2: one (c,b,ch) plane, 5 preloaded sweeps ---------
        __shared__ float s_c2t[Nn * 4];        // [n][l]
        __shared__ float sred2[4 * 12 * 65];   // [row=l*12+t][m], stride 65 -> conflict-free
        __shared__ float sred3[48 * 5];        // [row][g], stride 5
        int c = bx - 10;
        const float* c2 = ch ? hc2 : lc2;
        for (int j = tid; j < Nn * 4; j += 192) s_c2t[j] = c2[(j & 3) * Nn + (j >> 2)];
        __syncthreads();
        const float4* pb = (const float4*)X + (size_t)(b * Cc + c) * NF4;
        float4 x0 = pb[tid];
        float4 x1 = pb[tid + 192];
        float4 x2 = pb[tid + 384];
        float4 x3 = pb[tid + 576];
        float4 x4 = {0.f, 0.f, 0.f, 0.f};
        if (tid + 768 < NF4) x4 = pb[tid + 768];
        float4 a0 = {0.f, 0.f, 0.f, 0.f}, a1 = a0, a2 = a0, a3 = a0;
#define PROC(xq, ff)                                                           \
    {                                                                          \
        int n = (ff) / 3; if (n > 306) n = 306;                                \
        float4 wq = *(const float4*)&s_c2t[n * 4];                             \
        a0.x += xq.x * wq.x; a0.y += xq.y * wq.x; a0.z += xq.z * wq.x; a0.w += xq.w * wq.x; \
        a1.x += xq.x * wq.y; a1.y += xq.y * wq.y; a1.z += xq.z * wq.y; a1.w += xq.w * wq.y; \
        a2.x += xq.x * wq.z; a2.y += xq.y * wq.z; a2.z += xq.z * wq.z; a2.w += xq.w * wq.z; \
        a3.x += xq.x * wq.w; a3.y += xq.y * wq.w; a3.z += xq.z * wq.w; a3.w += xq.w * wq.w; \
    }
        PROC(x0, tid);
        PROC(x1, tid + 192);
        PROC(x2, tid + 384);
        PROC(x3, tid + 576);
        PROC(x4, tid + 768);
#undef PROC
        int tg = tid % 3, m = tid / 3;
        sred2[(0 * 12 + 4 * tg + 0) * 65 + m] = a0.x;
        sred2[(0 * 12 + 4 * tg + 1) * 65 + m] = a0.y;
        sred2[(0 * 12 + 4 * tg + 2) * 65 + m] = a0.z;
        sred2[(0 * 12 + 4 * tg + 3) * 65 + m] = a0.w;
        sred2[(1 * 12 + 4 * tg + 0) * 65 + m] = a1.x;
        sred2[(1 * 12 + 4 * tg + 1) * 65 + m] = a1.y;
        sred2[(1 * 12 + 4 * tg + 2) * 65 + m] = a1.z;
        sred2[(1 * 12 + 4 * tg + 3) * 65 + m] = a1.w;
        sred2[(2 * 12 + 4 * tg + 0) * 65 + m] = a2.x;
        sred2[(2 * 12 + 4 * tg + 1) * 65 + m] = a2.y;
        sred2[(2 * 12 + 4 * tg + 2) * 65 + m] = a2.z;
        sred2[(2 * 12 + 4 * tg + 3) * 65 + m] = a2.w;
        sred2[(3 * 12 + 4 * tg + 0) * 65 + m] = a3.x;
        sred2[(3 * 12 + 4 * tg + 1) * 65 + m] = a3.y;
        sred2[(3 * 12 + 4 * tg + 2) * 65 + m] = a3.z;
        sred2[(3 * 12 + 4 * tg + 3) * 65 + m] = a3.w;
        __syncthreads();
        {   // stage 1: 192 threads, each sums 16 slots of one row
            int j = tid >> 2, g = tid & 3;
            const float* r = &sred2[j * 65 + g * 16];
            float v = 0.f;
#pragma unroll
            for (int k = 0; k < 16; ++k) v += r[k];
            sred3[j * 5 + g] = v;
        }
        __syncthreads();
        if (tid < 48) {
            int l = tid / 12, t = tid % 12;
            const float* r = &sred3[tid * 5];
            float v = r[0] + r[1] + r[2] + r[3];
            int t0 = t + ch;
            G2[((size_t)(ch * LAYERS + l) * Bn + b) * (LH * Cc) + (size_t)t0 * Cc + c] = v;
        } else if (ch && tid < 52) {
            int l = tid - 48;
            G2[((size_t)(ch * LAYERS + l) * Bn + b) * (LH * Cc) + c] = 0.f;
        }
    }
}

// ============================================================================
// GW[ch][l][row=(b*LH+t0)][c] = sum_n (G1p0+G1p1)[ch][l][row][n] * w[ch][l][n][c]
// ============================================================================
#define GWR 4
__global__ __launch_bounds__(256) void k_gw(const float* __restrict__ lw,
                                            const float* __restrict__ hw,
                                            const float* __restrict__ G1,
                                            float* __restrict__ GW) {
    __shared__ float sG1[GWR * Nn];
    __shared__ float sred[8][GWR][Cc];  // 16 KB
    int tile = blockIdx.x;  // 0..103
    int chl = blockIdx.y;   // ch*4 + l
    int ch = chl >> 2, l = chl & 3;
    const float* w = (ch ? hw : lw) + (size_t)l * Nn * Cc;
    size_t g1off = (size_t)chl * Bn * (LH * Nn) + (size_t)tile * GWR * Nn;
    const float4* g1a = (const float4*)(G1 + g1off);
    const float4* g1b = (const float4*)(G1 + G1SZ + g1off);
    int tid = threadIdx.x;
    for (int i = tid; i < GWR * Nn / 4; i += 256) {
        float4 pa = g1a[i], pb = g1b[i];
        float4 s = {pa.x + pb.x, pa.y + pb.y, pa.z + pb.z, pa.w + pb.w};
        ((float4*)sG1)[i] = s;
    }
    __syncthreads();
    int c4 = (tid & 31) * 4;
    int stripe = tid >> 5;
    float4 a0 = {0.f, 0.f, 0.f, 0.f}, a1 = a0, a2 = a0, a3 = a0;
#define GW_FMA(wv, nn)                                         \
    {                                                          \
        float g0 = sG1[0 * Nn + (nn)];                         \
        float g1v = sG1[1 * Nn + (nn)];                        \
        float g2v = sG1[2 * Nn + (nn)];                        \
        float g3v = sG1[3 * Nn + (nn)];                        \
        a0.x += wv.x * g0;  a0.y += wv.y * g0;                 \
        a0.z += wv.z * g0;  a0.w += wv.w * g0;                 \
        a1.x += wv.x * g1v; a1.y += wv.y * g1v;                \
        a1.z += wv.z * g1v; a1.w += wv.w * g1v;                \
        a2.x += wv.x * g2v; a2.y += wv.y * g2v;                \
        a2.z += wv.z * g2v; a2.w += wv.w * g2v;                \
        a3.x += wv.x * g3v; a3.y += wv.y * g3v;                \
        a3.z += wv.z * g3v; a3.w += wv.w * g3v;                \
    }
    int n = stripe;
    for (; n + 24 < Nn; n += 32) {
        float4 w0 = *(const float4*)(w + (size_t)n * Cc + c4);
        float4 w1 = *(const float4*)(w + (size_t)(n + 8) * Cc + c4);
        float4 w2 = *(const float4*)(w + (size_t)(n + 16) * Cc + c4);
        float4 w3 = *(const float4*)(w + (size_t)(n + 24) * Cc + c4);
        GW_FMA(w0, n);
        GW_FMA(w1, n + 8);
        GW_FMA(w2, n + 16);
        GW_FMA(w3, n + 24);
    }
    for (; n < Nn; n += 8) {
        float4 w0 = *(const float4*)(w + (size_t)n * Cc + c4);
        GW_FMA(w0, n);
    }
#undef GW_FMA
    *(float4*)&sred[stripe][0][c4] = a0;
    *(float4*)&sred[stripe][1][c4] = a1;
    *(float4*)&sred[stripe][2][c4] = a2;
    *(float4*)&sred[stripe][3][c4] = a3;
    __syncthreads();
    float* out = GW + (size_t)chl * Bn * (LH * Cc) + (size_t)tile * GWR * Cc;
    for (int o = tid; o < GWR * Cc; o += 256) {
        int r = o >> 7, cc = o & 127;
        float v = 0.f;
#pragma unroll
        for (int s = 0; s < 8; ++s) v += sred[s][r][cc];
        out[o] = v;
    }
}

// ============================================================================
// k_m: M = GW . G2^T ; l==0 blocks run the layer-0 prologue (fused k_first).
// ============================================================================
__global__ __launch_bounds__(256) void k_m(const float* __restrict__ GW,
                                           const float* __restrict__ G2,
                                           const float* __restrict__ lb,
                                           const float* __restrict__ lv,
                                           const float* __restrict__ hb,
                                           const float* __restrict__ hv,
                                           float* __restrict__ M,
                                           float* __restrict__ Lg,
                                           float* __restrict__ Stats) {
    __shared__ float sGW[LH][SCW];
    __shared__ float sG2[LH][SCW];
    __shared__ float sMm[LH * LH];
    __shared__ float sS[LH * LH];
    __shared__ float sA[LH * LH];
    int blk = blockIdx.x;  // (ch*LAYERS + l)*Bn + b
    int ch = blk >> 7;
    int l = (blk >> 5) & 3;
    int b = blk & 31;
    int T = ch ? LH : Ll;
    const float* gw = GW + (size_t)blk * (LH * Cc);
    const float* g2 = G2 + (size_t)blk * (LH * Cc);
    int tid = threadIdx.x;
    for (int i = tid; i < LH * Cc; i += 256) {
        int t = i >> 7, c = i & 127;
        sGW[t][c] = gw[i];
        sG2[t][c] = g2[i];
    }
    __syncthreads();
    float* Mo = M + (size_t)blk * (LH * LH);
    if (tid < T * T) {
        int t0 = tid / T, t1 = tid % T;
        float a = 0.f;
#pragma unroll 8
        for (int cc = 0; cc < Cc; ++cc) a += sGW[t0][cc] * sG2[t1][cc];
        Mo[t0 * LH + t1] = a;
        sMm[t0 * LH + t1] = a;
    }
    if (l != 0) return;
    const float* bb = ch ? hb : lb;
    const float* v = ch ? hv : lv;
    __syncthreads();
    int TT = T * T;
    if (tid < TT) {
        int t = tid / T, q = tid % T;
        float a = bb[tid] + sMm[t * LH + q];
        sS[tid] = 1.f / (1.f + expf(-a));
    }
    __syncthreads();
    if (tid < TT) {
        int t = tid / T, q = tid % T;
        float a = 0.f;
        for (int k = 0; k < T; ++k) a += v[t * T + k] * sS[k * T + q];
        sA[tid] = a;
        Lg[(size_t)(ch * Bn + b) * (LH * LH) + tid] = a;
    }
    __syncthreads();
    if (tid < T) {
        float s = 0.f, ss = 0.f;
        for (int t = 0; t < T; ++t) {
            float x = sA[t * T + tid];
            s += x;
            ss += x * x;
        }
        float* St = Stats + (size_t)(0 * 2 + ch) * 2 * (LH * Bn);
        St[tid * Bn + b] = s;
        St[LH * Bn + tid * Bn + b] = ss;
    }
}

// ============================================================================
// Chain mids/last: grid-wide launches (64 blocks = one per (ch,b)).
// Kernel boundaries provide the cross-b sync BatchNorm needs. (verified r7)
// ============================================================================
template <int T>
__device__ __forceinline__ void mid_impl(int ch, int b, int l,
                                         const float* __restrict__ M,
                                         const float* __restrict__ bb_all,
                                         const float* __restrict__ v_all,
                                         const float* __restrict__ g_all,
                                         const float* __restrict__ be_all,
                                         float* __restrict__ Lg,
                                         float* __restrict__ Stats,
                                         float* __restrict__ Pws) {
    const int TT = T * T;
    __shared__ float sP[LH * LH], sC[LH * LH], sA[LH * LH], sB[LH * LH], sM[LH * LH];
    __shared__ float sMean[LH], sScale[LH], sShift[LH];
    int tid = threadIdx.x;
    bool first = (l == 0);
    float* Lgb = Lg + (size_t)(ch * Bn + b) * (LH * LH);
    float* Pb = Pws + (size_t)(ch * Bn + b) * (LH * LH);
    if (tid < T) {
        const float* St = Stats + (size_t)(l * 2 + ch) * 2 * (LH * Bn);
        float s = 0.f, ss = 0.f;
        for (int b2 = 0; b2 < Bn; ++b2) {
            s += St[tid * Bn + b2];
            ss += St[LH * Bn + tid * Bn + b2];
        }
        float inv = 1.f / (float)(Bn * T);
        float m = s * inv;
        float var = ss * inv - m * m;
        sMean[tid] = m;
        sScale[tid] = rsqrtf(var + BN_EPS) * g_all[l * T + tid];
        sShift[tid] = be_all[l * T + tid];
    }
    if (tid < TT) {
        sA[tid] = Lgb[tid];
        if (!first) sP[tid] = Pb[tid];
    }
    __syncthreads();
    if (tid < T) {
        float vals[T];
        float mx = -1e30f;
#pragma unroll
        for (int q = 0; q < T; ++q) {
            float x = (sA[tid * T + q] - sMean[q]) * sScale[q] + sShift[q];
            vals[q] = x;
            mx = fmaxf(mx, x);
        }
        float sm = 0.f;
#pragma unroll
        for (int q = 0; q < T; ++q) {
            vals[q] = expf(vals[q] - mx);
            sm += vals[q];
        }
        float inv = 1.f / sm;
#pragma unroll
        for (int q = 0; q < T; ++q) sC[tid * T + q] = vals[q] * inv;
    }
    __syncthreads();
    if (tid < TT) {
        int t0 = tid / T, q = tid % T;
        float a;
        if (first) {
            a = sC[q * T + t0];
        } else {
            a = 0.f;
#pragma unroll
            for (int t = 0; t < T; ++t) a += sP[t0 * T + t] * sC[q * T + t];
        }
        sB[tid] = a;
        Pb[tid] = a;
    }
    const float* Mn = M + ((size_t)(ch * LAYERS + l + 1) * Bn + b) * (LH * LH);
    for (int i = tid; i < T * LH; i += 192) sM[i] = Mn[i];
    __syncthreads();
    if (tid < TT) {
        int t = tid / T, t1 = tid % T;
        float a = 0.f;
#pragma unroll
        for (int t0 = 0; t0 < T; ++t0) a += sB[t0 * T + t] * sM[t0 * LH + t1];
        sA[tid] = a;
    }
    __syncthreads();
    const float* bbn = bb_all + (size_t)(l + 1) * TT;
    if (tid < TT) {
        int t = tid / T, q = tid % T;
        float a = bbn[tid];
#pragma unroll
        for (int t1 = 0; t1 < T; ++t1) a += sA[t * T + t1] * sB[t1 * T + q];
        sP[tid] = 1.f / (1.f + expf(-a));
    }
    __syncthreads();
    const float* vn = v_all + (size_t)(l + 1) * TT;
    if (tid < TT) {
        int t = tid / T, q = tid % T;
        float a = 0.f;
#pragma unroll
        for (int k = 0; k < T; ++k) a += vn[t * T + k] * sP[k * T + q];
        sA[tid] = a;
        Lgb[tid] = a;
    }
    __syncthreads();
    if (tid < T) {
        float s = 0.f, ss = 0.f;
#pragma unroll
        for (int t = 0; t < T; ++t) {
            float x = sA[t * T + tid];
            s += x;
            ss += x * x;
        }
        float* St = Stats + (size_t)((l + 1) * 2 + ch) * 2 * (LH * Bn);
        St[tid * Bn + b] = s;
        St[LH * Bn + tid * Bn + b] = ss;
    }
}

__global__ __launch_bounds__(192) void k_mid(const float* __restrict__ M,
                                             const float* __restrict__ lb,
                                             const float* __restrict__ lv,
                                             const float* __restrict__ lgam,
                                             const float* __restrict__ lbet,
                                             const float* __restrict__ hb,
                                             const float* __restrict__ hv,
                                             const float* __restrict__ hgam,
                                             const float* __restrict__ hbet,
                                             float* __restrict__ Lg,
                                             float* __restrict__ Stats,
                                             float* __restrict__ Pws, int l) {
    int ch = blockIdx.x >> 5, b = blockIdx.x & 31;
    if (ch == 0)
        mid_impl<Ll>(0, b, l, M, lb, lv, lgam, lbet, Lg, Stats, Pws);
    else
        mid_impl<LH>(1, b, l, M, hb, hv, hgam, hbet, Lg, Stats, Pws);
}

template <int T>
__device__ __forceinline__ void last_impl(int ch, int b,
                                          const float* __restrict__ g_all,
                                          const float* __restrict__ be_all,
                                          const float* __restrict__ Lg,
                                          const float* __restrict__ Stats,
                                          const float* __restrict__ Pws,
                                          float* __restrict__ Pcol) {
    const int TT = T * T;
    const int l = LAYERS - 1;
    __shared__ float sP[LH * LH], sC[LH * LH], sA[LH * LH], sB[LH * LH];
    __shared__ float sMean[LH], sScale[LH], sShift[LH];
    int tid = threadIdx.x;
    const float* Lgb = Lg + (size_t)(ch * Bn + b) * (LH * LH);
    const float* Pb = Pws + (size_t)(ch * Bn + b) * (LH * LH);
    if (tid < T) {
        const float* St = Stats + (size_t)(l * 2 + ch) * 2 * (LH * Bn);
        float s = 0.f, ss = 0.f;
        for (int b2 = 0; b2 < Bn; ++b2) {
            s += St[tid * Bn + b2];
            ss += St[LH * Bn + tid * Bn + b2];
        }
        float inv = 1.f / (float)(Bn * T);
        float m = s * inv;
        float var = ss * inv - m * m;
        sMean[tid] = m;
        sScale[tid] = rsqrtf(var + BN_EPS) * g_all[l * T + tid];
        sShift[tid] = be_all[l * T + tid];
    }
    if (tid < TT) {
        sA[tid] = Lgb[tid];
        sP[tid] = Pb[tid];
    }
    __syncthreads();
    if (tid < T) {
        float vals[T];
        float mx = -1e30f;
#pragma unroll
        for (int q = 0; q < T; ++q) {
            float x = (sA[tid * T + q] - sMean[q]) * sScale[q] + sShift[q];
            vals[q] = x;
            mx = fmaxf(mx, x);
        }
        float sm = 0.f;
#pragma unroll
        for (int q = 0; q < T; ++q) {
            vals[q] = expf(vals[q] - mx);
            sm += vals[q];
        }
        float inv = 1.f / sm;
#pragma unroll
        for (int q = 0; q < T; ++q) sC[tid * T + q] = vals[q] * inv;
    }
    __syncthreads();
    if (tid < TT) {
        int t0 = tid / T, q = tid % T;
        float a = 0.f;
#pragma unroll
        for (int t = 0; t < T; ++t) a += sP[t0 * T + t] * sC[q * T + t];
        sB[tid] = a;
    }
    __syncthreads();
    if (tid < T) Pcol[(size_t)ch * Bn * LH + b * LH + tid] = sB[tid * T + (T - 1)];
}

__global__ __launch_bounds__(192) void k_last(const float* __restrict__ lgam,
                                              const float* __restrict__ lbet,
                                              const float* __restrict__ hgam,
                                              const float* __restrict__ hbet,
                                              const float* __restrict__ Lg,
                                              const float* __restrict__ Stats,
                                              const float* __restrict__ Pws,
                                              float* __restrict__ Pcol) {
    int ch = blockIdx.x >> 5, b = blockIdx.x & 31;
    if (ch == 0)
        last_impl<Ll>(0, b, lgam, lbet, Lg, Stats, Pws, Pcol);
    else
        last_impl<LH>(1, b, hgam, hbet, Lg, Stats, Pws, Pcol);
}

// ============================================================================
// final: residuals + alpha blend; flat contiguous f4 streams + lane-triple
// LDS reduce; coalesced store. (unchanged, verified)
// ============================================================================
__global__ __launch_bounds__(192) void k_final(const float* __restrict__ XL,
                                               const float* __restrict__ XH,
                                               const float* __restrict__ Pcol,
                                               const float* __restrict__ alpha,
                                               float* __restrict__ out) {
    __shared__ float s_pl[Ll];
    __shared__ float s_ph[LH];
    __shared__ float sfin[192];
    int b = blockIdx.y;
    int tid = threadIdx.x;
    if (tid < Ll) s_pl[tid] = Pcol[b * LH + tid];
    if (tid >= 64 && tid < 64 + LH) s_ph[tid - 64] = Pcol[Bn * LH + b * LH + (tid - 64)];
    __syncthreads();
    int F = blockIdx.x * 192 + tid;
    int tg = F % 3;
    const float4* pl4 = (const float4*)XL + (size_t)b * (Cc * Nn * 3) + F;
    const float4* ph4 = (const float4*)XH + (size_t)b * (Cc * Nn * 3) + F;
    float4 xl = *pl4;
    float4 xh = *ph4;
    float a = 1.f / (1.f + expf(-alpha[0]));
    const float* wl = &s_pl[4 * tg];
    const float* wh = &s_ph[4 * tg + 1];
    float pL = xl.x * wl[0] + xl.y * wl[1] + xl.z * wl[2] + xl.w * wl[3];
    float pH = xh.x * wh[0] + xh.y * wh[1] + xh.z * wh[2] + xh.w * wh[3];
    float p = a * pL + (1.f - a) * pH;
    if (tg == 2) p += a * xl.w + (1.f - a) * xh.w;
    sfin[tid] = p;
    __syncthreads();
    if (tid < 64) {
        float v = sfin[3 * tid] + sfin[3 * tid + 1] + sfin[3 * tid + 2];
        out[(size_t)b * (Cc * Nn) + blockIdx.x * 64 + tid] = v;
    }
}

extern "C" void kernel_launch(void* const* d_in, const int* in_sizes, int n_in,
                              void* d_out, int out_size, void* d_ws, size_t ws_size,
                              hipStream_t stream) {
    const float* XL = (const float*)d_in[0];
    const float* XH = (const float*)d_in[1];
    const float* lc1 = (const float*)d_in[2];
    const float* lc2 = (const float*)d_in[3];
    const float* lw = (const float*)d_in[4];
    const float* lb = (const float*)d_in[5];
    const float* lv = (const float*)d_in[6];
    const float* lg = (const float*)d_in[7];
    const float* lbeta = (const float*)d_in[8];
    const float* hc1 = (const float*)d_in[9];
    const float* hc2 = (const float*)d_in[10];
    const float* hw = (const float*)d_in[11];
    const float* hb = (const float*)d_in[12];
    const float* hv = (const float*)d_in[13];
    const float* hg = (const float*)d_in[14];
    const float* hbeta = (const float*)d_in[15];
    const float* alpha = (const float*)d_in[16];
    float* out = (float*)d_out;

    float* ws = (float*)d_ws;
    float* G1 = ws;                                          // 2 partial buffers
    float* G2 = G1 + 2 * G1SZ;                               // 2*4*32*13*128
    float* M = G2 + (size_t)2 * LAYERS * Bn * LH * Cc;       // 2*4*32*13*13
    float* Pcol = M + (size_t)2 * LAYERS * Bn * LH * LH;     // 2*32*13
    float* Stats = Pcol + (size_t)2 * Bn * LH;               // 16*13*32
    float* Lg = Stats + (size_t)4 * LAYERS * LH * Bn;        // 2*32*169
    float* Pws = Lg + (size_t)2 * Bn * LH * LH;              // 2*32*169
    float* GW = Pws + (size_t)2 * Bn * LH * LH;              // 2*4*32*13*128

    k_gx<<<dim3(138, 32, 2), 192, 0, stream>>>(XL, XH, lc1, hc1, lc2, hc2, G1, G2);
    k_gw<<<dim3(104, 8), 256, 0, stream>>>(lw, hw, G1, GW);
    k_m<<<256, 256, 0, stream>>>(GW, G2, lb, lv, hb, hv, M, Lg, Stats);
    k_mid<<<64, 192, 0, stream>>>(M, lb, lv, lg, lbeta, hb, hv, hg, hbeta, Lg, Stats, Pws, 0);
    k_mid<<<64, 192, 0, stream>>>(M, lb, lv, lg, lbeta, hb, hv, hg, hbeta, Lg, Stats, Pws, 1);
    k_mid<<<64, 192, 0, stream>>>(M, lb, lv, lg, lbeta, hb, hv, hg, hbeta, Lg, Stats, Pws, 2);
    k_last<<<64, 192, 0, stream>>>(lg, lbeta, hg, hbeta, Lg, Stats, Pws, Pcol);
    k_final<<<dim3(614, 32), 192, 0, stream>>>(XL, XH, Pcol, alpha, out);
}